// Round 3
// baseline (35251.486 us; speedup 1.0000x reference)
//
#include <hip/hip_runtime.h>
#include <hip/hip_cooperative_groups.h>

namespace cg = cooperative_groups;

#define NB 8
#define NHID 256
#define LSEQ 50
#define NV 50257
#define NLAY 4
#define NFF 2048
#define BOSTOK 50256
#define LNEPS 1e-5f
#define NSTEP 49

// ---------------- cooperative path ----------------
#define NBLK 256
#define RPB 197  // ceil(50257/256)

// coop workspace float offsets
#define CWS_MEM   0
#define CWS_CA    2048
#define CWS_XIN   10240
#define CWS_XMID  12288
#define CWS_Q     14336
#define CWS_FFP   16384
#define CWS_KC    81920
#define CWS_VC    491520
#define CWS_PV    901120   // 2048
#define CWS_PI    903168   // 2048 ints

// fallback workspace float offsets (round-1 layout, proven)
#define WS_MEM 0
#define WS_CA  2048
#define WS_X   10240
#define WS_Q   12288
#define WS_FFP 14336
#define WS_KC  79872
#define WS_VC  489472
#define WS_PV  899072
#define WS_PI  905472
#define WS_TOK 911872
#define FCT 786

__device__ __forceinline__ float block_ln256(float v, int tid, float* red8, float g, float bta) {
  float s = v, s2 = v * v;
#pragma unroll
  for (int m = 32; m >= 1; m >>= 1) { s += __shfl_xor(s, m); s2 += __shfl_xor(s2, m); }
  int w = tid >> 6;
  __syncthreads();
  if ((tid & 63) == 0) { red8[w] = s; red8[4 + w] = s2; }
  __syncthreads();
  s = red8[0] + red8[1] + red8[2] + red8[3];
  s2 = red8[4] + red8[5] + red8[6] + red8[7];
  float mn = s * (1.0f / 256.0f);
  float var = s2 * (1.0f / 256.0f) - mn * mn;
  float rs = rsqrtf(var + LNEPS);
  return (v - mn) * rs * g + bta;
}

__global__ __launch_bounds__(256, 2) void k_persist(
    const float* __restrict__ emb, const float* __restrict__ w_proj, const float* __restrict__ b_proj,
    const float* __restrict__ tok_emb, const float* __restrict__ pos_enc,
    const float* __restrict__ sa_in_w, const float* __restrict__ sa_in_b,
    const float* __restrict__ sa_out_w, const float* __restrict__ sa_out_b,
    const float* __restrict__ ca_in_w, const float* __restrict__ ca_in_b,
    const float* __restrict__ ca_out_w, const float* __restrict__ ca_out_b,
    const float* __restrict__ ff1_w, const float* __restrict__ ff1_b,
    const float* __restrict__ ff2_w, const float* __restrict__ ff2_b,
    const float* __restrict__ ln_g, const float* __restrict__ ln_b,
    const float* __restrict__ fc_w, const float* __restrict__ fc_b,
    float* __restrict__ out, float* __restrict__ wsf, int* __restrict__ wsi) {
  cg::grid_group grid = cg::this_grid();
  const int bid = blockIdx.x, tid = threadIdx.x;

  float* mem  = wsf + CWS_MEM;
  float* ca   = wsf + CWS_CA;
  float* xin  = wsf + CWS_XIN;
  float* xmid = wsf + CWS_XMID;
  float* q    = wsf + CWS_Q;
  float* ffp  = wsf + CWS_FFP;
  float* kc   = wsf + CWS_KC;
  float* vc   = wsf + CWS_VC;
  float* pv   = wsf + CWS_PV;
  int*   pi   = wsi + CWS_PI;

  __shared__ float xl[8 * 260];
  __shared__ float h1l[64 * 9];
  __shared__ float ql[256], ol[256], ph[8 * 64];
  __shared__ float red8[8];
  __shared__ float rv[256];
  __shared__ int   ri[256];
  __shared__ int   toks[8];
  __shared__ float el[1536];

  // init 1: mem = embedding @ w_proj.T + b_proj
  if (bid < 64) {
    int b = bid >> 3, tile = bid & 7;
    for (int k = tid; k < 1536; k += 256) el[k] = emb[b * 1536 + k];
    __syncthreads();
    int r = tid >> 3, g = tid & 7;
    int row = tile * 32 + r;
    float acc = 0.f;
    const float* wr = w_proj + (size_t)row * 1536;
    for (int c = g * 192; c < g * 192 + 192; ++c) acc += wr[c] * el[c];
    rv[tid] = acc;
    __syncthreads();
    for (int off = 4; off >= 1; off >>= 1) {
      if (g < off) rv[tid] += rv[tid + off];
      __syncthreads();
    }
    if (g == 0) mem[b * 256 + row] = rv[tid] + b_proj[row];
  }
  grid.sync();

  // init 2: cross-attn constant (mem len 1 => attn == V_mem)
  if (bid < 32) {
    int l = bid >> 3, b = bid & 7;
    ql[tid] = mem[b * 256 + tid];
    __syncthreads();
    float acc = ca_in_b[l * 768 + 512 + tid];
    const float* wr = ca_in_w + (size_t)(l * 768 + 512 + tid) * 256;
    for (int c = 0; c < 256; ++c) acc += wr[c] * ql[c];
    ol[tid] = acc;
    __syncthreads();
    float acc2 = ca_out_b[l * 256 + tid];
    const float* wr2 = ca_out_w + (size_t)(l * 256 + tid) * 256;
    for (int c = 0; c < 256; ++c) acc2 += wr2[c] * ol[c];
    ca[(l * 8 + b) * 256 + tid] = acc2;
  }
  grid.sync();

  for (int t = 0; t < NSTEP; ++t) {
    for (int l = 0; l < NLAY; ++l) {
      // Phase A (blocks 0..23): prologue -> xl; blocks 0..7 publish xin; qkv GEMV
      if (bid < 24) {
        if (l == 0) {
          if (t == 0) {
            if (tid < 8) toks[tid] = BOSTOK;
            __syncthreads();
          } else {
            int b = tid & 7, i0 = tid >> 3;
            float bv = -3e38f; int bi = 2147483647;
            for (int p = i0; p < NBLK; p += 32) {
              float v = pv[p * 8 + b]; int id = pi[p * 8 + b];
              if (v > bv || (v == bv && id < bi)) { bv = v; bi = id; }
            }
            rv[tid] = bv; ri[tid] = bi;
            __syncthreads();
            for (int off = 128; off >= 8; off >>= 1) {
              if (tid < off) {
                float v = rv[tid + off]; int id = ri[tid + off];
                if (v > rv[tid] || (v == rv[tid] && id < ri[tid])) { rv[tid] = v; ri[tid] = id; }
              }
              __syncthreads();
            }
            if (tid < 8) toks[tid] = ri[tid];
            __syncthreads();
          }
          for (int b = 0; b < 8; ++b)
            xl[b * 260 + tid] = tok_emb[(size_t)toks[b] * 256 + tid] + pos_enc[t * 256 + tid];
        } else {
          const float* lg = ln_g + ((l - 1) * 3 + 2) * 256;
          const float* lb = ln_b + ((l - 1) * 3 + 2) * 256;
          for (int b = 0; b < 8; ++b) {
            float a = xmid[b * 256 + tid] + ff2_b[(l - 1) * 256 + tid];
            for (int s = 0; s < 32; ++s) a += ffp[(s * 8 + b) * 256 + tid];
            xl[b * 260 + tid] = block_ln256(a, tid, red8, lg[tid], lb[tid]);
          }
        }
        __syncthreads();
        if (bid < 8) xin[bid * 256 + tid] = xl[bid * 260 + tid];
        int r = tid >> 3, b8 = tid & 7;
        int row = bid * 32 + r;
        float acc = sa_in_b[l * 768 + row];
        const float4* w4 = reinterpret_cast<const float4*>(sa_in_w + (size_t)(l * 768 + row) * 256);
        const float4* xv = reinterpret_cast<const float4*>(xl + b8 * 260);
#pragma unroll 8
        for (int k = 0; k < 64; ++k) {
          float4 wv = w4[k]; float4 xq = xv[k];
          acc += wv.x * xq.x + wv.y * xq.y + wv.z * xq.z + wv.w * xq.w;
        }
        if (row < 256) {
          q[b8 * 256 + row] = acc;
        } else if (row < 512) {
          int h = (row - 256) >> 5, d = (row - 256) & 31;
          kc[(((size_t)(l * 8 + b8) * 8 + h) * 50 + t) * 32 + d] = acc;
        } else {
          int h = (row - 512) >> 5, d = (row - 512) & 31;
          vc[(((size_t)(l * 8 + b8) * 8 + h) * 50 + t) * 32 + d] = acc;
        }
      }
      grid.sync();

      // Phase B (blocks 0..7): attention + out-proj + LN1 + ca + LN2 -> xmid
      if (bid < 8) {
        int b = bid;
        float xres = xin[b * 256 + tid];
        ql[tid] = q[b * 256 + tid];
        __syncthreads();
        int h = tid >> 5, lane = tid & 31;
        const float* kb = kc + ((size_t)(l * 8 + b) * 8 + h) * 50 * 32;
        const float* vb = vc + ((size_t)(l * 8 + b) * 8 + h) * 50 * 32;
        float s0 = -3e38f, s1 = -3e38f;
        {
          const float* qh = ql + h * 32;
          if (lane <= t) {
            float d0 = 0.f;
            const float* kr = kb + lane * 32;
#pragma unroll
            for (int d = 0; d < 32; ++d) d0 += qh[d] * kr[d];
            s0 = d0 * 0.17677669529663687f;
          }
          if (lane + 32 <= t) {
            float d1 = 0.f;
            const float* kr = kb + (lane + 32) * 32;
#pragma unroll
            for (int d = 0; d < 32; ++d) d1 += qh[d] * kr[d];
            s1 = d1 * 0.17677669529663687f;
          }
        }
        float mx = fmaxf(s0, s1);
        for (int m = 16; m >= 1; m >>= 1) mx = fmaxf(mx, __shfl_xor(mx, m, 32));
        float e0 = (lane <= t) ? expf(s0 - mx) : 0.f;
        float e1 = (lane + 32 <= t) ? expf(s1 - mx) : 0.f;
        float sm = e0 + e1;
        for (int m = 16; m >= 1; m >>= 1) sm += __shfl_xor(sm, m, 32);
        ph[h * 64 + lane] = e0;
        ph[h * 64 + lane + 32] = e1;
        __syncthreads();
        float o = 0.f;
        for (int j = 0; j <= t; ++j) o += ph[h * 64 + j] * vb[j * 32 + lane];
        ol[h * 32 + lane] = o / sm;
        __syncthreads();
        float acc = sa_out_b[l * 256 + tid];
        const float4* w4 = reinterpret_cast<const float4*>(sa_out_w + (size_t)(l * 256 + tid) * 256);
#pragma unroll 4
        for (int k = 0; k < 64; ++k) {
          float4 wv = w4[k];
          acc += wv.x * ol[4 * k] + wv.y * ol[4 * k + 1] + wv.z * ol[4 * k + 2] + wv.w * ol[4 * k + 3];
        }
        acc += xres;
        float y = block_ln256(acc, tid, red8, ln_g[(l * 3 + 0) * 256 + tid], ln_b[(l * 3 + 0) * 256 + tid]);
        float acc2 = y + ca[(l * 8 + b) * 256 + tid];
        float y2 = block_ln256(acc2, tid, red8, ln_g[(l * 3 + 1) * 256 + tid], ln_b[(l * 3 + 1) * 256 + tid]);
        xmid[b * 256 + tid] = y2;
      }
      grid.sync();

      // Phase C (blocks 0..31): FFN slice -> partials
      if (bid < 32) {
        int s = bid;
        for (int b = 0; b < 8; ++b) xl[b * 260 + tid] = xmid[b * 256 + tid];
        __syncthreads();
        int n0 = tid >> 3, b = tid & 7;
#pragma unroll
        for (int i = 0; i < 2; ++i) {
          int nn = n0 + i * 32, row = s * 64 + nn;
          float acc = ff1_b[l * 2048 + row];
          const float4* w4 = reinterpret_cast<const float4*>(ff1_w + (size_t)(l * 2048 + row) * 256);
          const float4* xv = reinterpret_cast<const float4*>(xl + b * 260);
          for (int k = 0; k < 64; ++k) {
            float4 wv = w4[k]; float4 xq = xv[k];
            acc += wv.x * xq.x + wv.y * xq.y + wv.z * xq.z + wv.w * xq.w;
          }
          h1l[nn * 9 + b] = fmaxf(acc, 0.f);
        }
        __syncthreads();
        float acc[8] = {0, 0, 0, 0, 0, 0, 0, 0};
        const float* w2p = ff2_w + (size_t)(l * 256 + tid) * 2048 + s * 64;
        for (int n = 0; n < 64; ++n) {
          float wv = w2p[n];
#pragma unroll
          for (int b2 = 0; b2 < 8; ++b2) acc[b2] += wv * h1l[n * 9 + b2];
        }
        for (int b2 = 0; b2 < 8; ++b2) ffp[(s * 8 + b2) * 256 + tid] = acc[b2];
      }
      grid.sync();
    }

    // Phase D (blocks 0..7): last FFN reduce + LN -> xin
    if (bid < 8) {
      int b = bid;
      float a = xmid[b * 256 + tid] + ff2_b[3 * 256 + tid];
      for (int s = 0; s < 32; ++s) a += ffp[(s * 8 + b) * 256 + tid];
      xin[b * 256 + tid] = block_ln256(a, tid, red8, ln_g[(3 * 3 + 2) * 256 + tid], ln_b[(3 * 3 + 2) * 256 + tid]);
    }
    grid.sync();

    // Phase E (all blocks): vocab GEMV + logits + per-block argmax
    {
      for (int b = 0; b < 8; ++b) xl[b * 260 + tid] = xin[b * 256 + tid];
      __syncthreads();
      int r = tid >> 3, b = tid & 7;
      float bv = -3e38f; int bi = 2147483647;
      int base = bid * RPB;
      for (int i = 0; i < 7; ++i) {
        int rr = i * 32 + r;
        int row = base + rr;
        if (rr < RPB && row < NV) {
          float acc = fc_b[row];
          const float4* w4 = reinterpret_cast<const float4*>(fc_w + (size_t)row * 256);
          const float4* xv = reinterpret_cast<const float4*>(xl + b * 260);
          for (int k = 0; k < 64; ++k) {
            float4 wv = w4[k]; float4 xq = xv[k];
            acc += wv.x * xq.x + wv.y * xq.y + wv.z * xq.z + wv.w * xq.w;
          }
          out[(size_t)(b * 49 + t) * NV + row] = acc;
          if (acc > bv || (acc == bv && row < bi)) { bv = acc; bi = row; }
        }
      }
      rv[tid] = bv; ri[tid] = bi;
      __syncthreads();
      for (int off = 128; off >= 8; off >>= 1) {
        if (tid < off) {
          float v = rv[tid + off]; int id = ri[tid + off];
          if (v > rv[tid] || (v == rv[tid] && id < ri[tid])) { rv[tid] = v; ri[tid] = id; }
        }
        __syncthreads();
      }
      if (tid < 8) { pv[bid * 8 + tid] = rv[tid]; pi[bid * 8 + tid] = ri[tid]; }
    }
    grid.sync();
  }
}

// ---------------- fallback path (round-1, proven) ----------------

__device__ __forceinline__ float block_ln(float v, int tid, float* red, float* red2,
                                          float g, float bta) {
  red[tid] = v; red2[tid] = v * v;
  __syncthreads();
  for (int off = 128; off > 0; off >>= 1) {
    if (tid < off) { red[tid] += red[tid + off]; red2[tid] += red2[tid + off]; }
    __syncthreads();
  }
  float m = red[0] * (1.0f / 256.0f);
  float var = red2[0] * (1.0f / 256.0f) - m * m;
  float rs = rsqrtf(var + LNEPS);
  float y = (v - m) * rs * g + bta;
  __syncthreads();
  return y;
}

__global__ __launch_bounds__(256) void k_mem(const float* __restrict__ emb,
                                             const float* __restrict__ w,
                                             const float* __restrict__ bias,
                                             float* __restrict__ mem) {
  __shared__ float el[1536];
  __shared__ float red[256];
  int b = blockIdx.x >> 3, tile = blockIdx.x & 7, tid = threadIdx.x;
  for (int k = tid; k < 1536; k += 256) el[k] = emb[b * 1536 + k];
  __syncthreads();
  int r = tid >> 3, g = tid & 7;
  int row = tile * 32 + r;
  float acc = 0.f;
  const float* wr = w + row * 1536;
  for (int c = g * 192; c < g * 192 + 192; ++c) acc += wr[c] * el[c];
  red[tid] = acc;
  __syncthreads();
  for (int off = 4; off >= 1; off >>= 1) {
    if (g < off) red[tid] += red[tid + off];
    __syncthreads();
  }
  if (g == 0) mem[b * 256 + row] = red[tid] + bias[row];
}

__global__ __launch_bounds__(256) void k_ca(const float* __restrict__ mem,
                                            const float* __restrict__ iw,
                                            const float* __restrict__ ib,
                                            const float* __restrict__ ow,
                                            const float* __restrict__ ob,
                                            float* __restrict__ ca) {
  __shared__ float ml[256], vl[256];
  int l = blockIdx.x >> 3, b = blockIdx.x & 7, tid = threadIdx.x;
  ml[tid] = mem[b * 256 + tid];
  __syncthreads();
  float acc = ib[l * 768 + 512 + tid];
  const float* wr = iw + (size_t)(l * 768 + 512 + tid) * 256;
  for (int c = 0; c < 256; ++c) acc += wr[c] * ml[c];
  vl[tid] = acc;
  __syncthreads();
  float acc2 = ob[l * 256 + tid];
  const float* wr2 = ow + (size_t)(l * 256 + tid) * 256;
  for (int c = 0; c < 256; ++c) acc2 += wr2[c] * vl[c];
  ca[(l * 8 + b) * 256 + tid] = acc2;
}

__global__ void k_tok_init(int* __restrict__ tok) {
  if (threadIdx.x < 8) tok[threadIdx.x * 64] = BOSTOK;
}

__global__ __launch_bounds__(256) void k_embed(const int* __restrict__ tok,
                                               const float* __restrict__ te,
                                               const float* __restrict__ pe,
                                               float* __restrict__ x, int t) {
  int tid = threadIdx.x;
  for (int b = 0; b < 8; ++b) {
    int tk = tok[b * 64 + t];
    x[b * 256 + tid] = te[(size_t)tk * 256 + tid] + pe[t * 256 + tid];
  }
}

__global__ __launch_bounds__(256) void k_qkv(const float* __restrict__ x,
                                             const float* __restrict__ w,
                                             const float* __restrict__ bias,
                                             float* __restrict__ q,
                                             float* __restrict__ kc,
                                             float* __restrict__ vc, int l, int t) {
  __shared__ float xl[8 * 260];
  int tid = threadIdx.x;
  for (int k = 0; k < 8; ++k) {
    int idx = tid + k * 256;
    xl[(idx >> 8) * 260 + (idx & 255)] = x[idx];
  }
  __syncthreads();
  int r = tid >> 3, b = tid & 7;
  int row = blockIdx.x * 32 + r;
  float acc = bias[l * 768 + row];
  const float4* w4 = reinterpret_cast<const float4*>(w + (size_t)(l * 768 + row) * 256);
  const float4* xv = reinterpret_cast<const float4*>(xl + b * 260);
#pragma unroll 8
  for (int k = 0; k < 64; ++k) {
    float4 wv = w4[k]; float4 xq = xv[k];
    acc += wv.x * xq.x + wv.y * xq.y + wv.z * xq.z + wv.w * xq.w;
  }
  if (row < 256) {
    q[b * 256 + row] = acc;
  } else if (row < 512) {
    int h = (row - 256) >> 5, d = (row - 256) & 31;
    kc[(((l * 8 + b) * 8 + h) * 50 + t) * 32 + d] = acc;
  } else {
    int h = (row - 512) >> 5, d = (row - 512) & 31;
    vc[(((l * 8 + b) * 8 + h) * 50 + t) * 32 + d] = acc;
  }
}

__global__ __launch_bounds__(256) void k_attn(const float* __restrict__ q,
                                              float* __restrict__ x,
                                              const float* __restrict__ kc,
                                              const float* __restrict__ vc,
                                              const float* __restrict__ ow,
                                              const float* __restrict__ ob,
                                              const float* __restrict__ lg,
                                              const float* __restrict__ lb,
                                              const float* __restrict__ ca, int l, int t) {
  __shared__ float ql[256], ol[256], sc[64], red[256], red2[256];
  __shared__ float ssum;
  int b = blockIdx.x, tid = threadIdx.x;
  float xres = x[b * 256 + tid];
  ql[tid] = q[b * 256 + tid];
  __syncthreads();
  for (int h = 0; h < 8; ++h) {
    const float* kb = kc + (size_t)(((l * 8 + b) * 8 + h) * 50) * 32;
    if (tid <= t) {
      float s = 0.f;
      const float* kr = kb + tid * 32;
#pragma unroll
      for (int d = 0; d < 32; ++d) s += ql[h * 32 + d] * kr[d];
      sc[tid] = s * 0.17677669529663687f;
    }
    __syncthreads();
    if (tid < 64) {
      float v = (tid <= t) ? sc[tid] : -1e30f;
      float mx = v;
      for (int m = 32; m >= 1; m >>= 1) mx = fmaxf(mx, __shfl_xor(mx, m));
      float e = (tid <= t) ? expf(sc[tid] - mx) : 0.f;
      sc[tid] = e;
      float sm = e;
      for (int m = 32; m >= 1; m >>= 1) sm += __shfl_xor(sm, m);
      if (tid == 0) ssum = sm;
    }
    __syncthreads();
    if (tid < 32) {
      const float* vb = vc + (size_t)(((l * 8 + b) * 8 + h) * 50) * 32 + tid;
      float acc = 0.f;
      for (int j = 0; j <= t; ++j) acc += sc[j] * vb[j * 32];
      ol[h * 32 + tid] = acc / ssum;
    }
    __syncthreads();
  }
  float acc = ob[l * 256 + tid];
  const float4* w4 = reinterpret_cast<const float4*>(ow + (size_t)(l * 256 + tid) * 256);
#pragma unroll 4
  for (int k = 0; k < 64; ++k) {
    float4 wv = w4[k];
    acc += wv.x * ol[4 * k] + wv.y * ol[4 * k + 1] + wv.z * ol[4 * k + 2] + wv.w * ol[4 * k + 3];
  }
  acc += xres;
  float y = block_ln(acc, tid, red, red2, lg[(l * 3 + 0) * 256 + tid], lb[(l * 3 + 0) * 256 + tid]);
  float acc2 = y + ca[(l * 8 + b) * 256 + tid];
  float y2 = block_ln(acc2, tid, red, red2, lg[(l * 3 + 1) * 256 + tid], lb[(l * 3 + 1) * 256 + tid]);
  x[b * 256 + tid] = y2;
}

__global__ __launch_bounds__(256) void k_ffn(const float* __restrict__ x,
                                             const float* __restrict__ w1,
                                             const float* __restrict__ b1,
                                             const float* __restrict__ w2,
                                             float* __restrict__ ffp, int l) {
  __shared__ float xl[8 * 260];
  __shared__ float h1l[64 * 9];
  int tid = threadIdx.x, s = blockIdx.x;
  for (int k = 0; k < 8; ++k) {
    int idx = tid + k * 256;
    xl[(idx >> 8) * 260 + (idx & 255)] = x[idx];
  }
  __syncthreads();
  int n0 = tid >> 3, b = tid & 7;
#pragma unroll
  for (int i = 0; i < 2; ++i) {
    int nn = n0 + i * 32, row = s * 64 + nn;
    float acc = b1[l * 2048 + row];
    const float4* w4 = reinterpret_cast<const float4*>(w1 + (size_t)(l * 2048 + row) * 256);
    const float4* xv = reinterpret_cast<const float4*>(xl + b * 260);
    for (int k = 0; k < 64; ++k) {
      float4 wv = w4[k]; float4 xq = xv[k];
      acc += wv.x * xq.x + wv.y * xq.y + wv.z * xq.z + wv.w * xq.w;
    }
    h1l[nn * 9 + b] = fmaxf(acc, 0.f);
  }
  __syncthreads();
  int row = tid;
  float acc[8] = {0, 0, 0, 0, 0, 0, 0, 0};
  const float* w2p = w2 + (size_t)(l * 256 + row) * 2048 + s * 64;
  for (int n = 0; n < 64; ++n) {
    float wv = w2p[n];
#pragma unroll
    for (int b2 = 0; b2 < 8; ++b2) acc[b2] += wv * h1l[n * 9 + b2];
  }
  for (int b2 = 0; b2 < 8; ++b2) ffp[(s * 8 + b2) * 256 + row] = acc[b2];
}

__global__ __launch_bounds__(256) void k_ffred(float* __restrict__ x,
                                               const float* __restrict__ ffp,
                                               const float* __restrict__ b2,
                                               const float* __restrict__ lg,
                                               const float* __restrict__ lb, int l) {
  __shared__ float red[256], red2[256];
  int b = blockIdx.x, tid = threadIdx.x;
  float acc = b2[l * 256 + tid] + x[b * 256 + tid];
  for (int s = 0; s < 32; ++s) acc += ffp[(s * 8 + b) * 256 + tid];
  float y = block_ln(acc, tid, red, red2, lg[(l * 3 + 2) * 256 + tid], lb[(l * 3 + 2) * 256 + tid]);
  x[b * 256 + tid] = y;
}

__global__ __launch_bounds__(256) void k_fc(const float* __restrict__ h,
                                            const float* __restrict__ w,
                                            const float* __restrict__ bias,
                                            float* __restrict__ out,
                                            float* __restrict__ pv,
                                            int* __restrict__ pi, int t) {
  __shared__ float hl[8 * 260];
  __shared__ float rv[256];
  __shared__ int ri[256];
  int tid = threadIdx.x, wg = blockIdx.x;
  for (int k = 0; k < 8; ++k) {
    int idx = tid + k * 256;
    hl[(idx >> 8) * 260 + (idx & 255)] = h[idx];
  }
  __syncthreads();
  int r = tid >> 3, b = tid & 7;
  float bv = -3e38f;
  int bi = 2147483647;
  for (int i = 0; i < 2; ++i) {
    int row = wg * 64 + i * 32 + r;
    if (row < NV) {
      float acc = bias[row];
      const float4* w4 = reinterpret_cast<const float4*>(w + (size_t)row * 256);
      const float4* xv = reinterpret_cast<const float4*>(hl + b * 260);
      for (int k = 0; k < 64; ++k) {
        float4 wv = w4[k]; float4 xq = xv[k];
        acc += wv.x * xq.x + wv.y * xq.y + wv.z * xq.z + wv.w * xq.w;
      }
      out[(size_t)(b * 49 + t) * NV + row] = acc;
      if (acc > bv || (acc == bv && row < bi)) { bv = acc; bi = row; }
    }
  }
  rv[tid] = bv; ri[tid] = bi;
  __syncthreads();
  for (int off = 128; off >= 8; off >>= 1) {
    if (tid < off) {
      float v = rv[tid + off]; int id = ri[tid + off];
      if (v > rv[tid] || (v == rv[tid] && id < ri[tid])) { rv[tid] = v; ri[tid] = id; }
    }
    __syncthreads();
  }
  if (tid < 8) { pv[wg * 8 + tid] = rv[tid]; pi[wg * 8 + tid] = ri[tid]; }
}

__global__ __launch_bounds__(256) void k_amax(const float* __restrict__ pv,
                                              const int* __restrict__ pi,
                                              int* __restrict__ tok, int t) {
  __shared__ float rv[256];
  __shared__ int ri[256];
  int tid = threadIdx.x, b = tid & 7, i0 = tid >> 3;
  float bv = -3e38f;
  int bi = 2147483647;
  for (int p = i0; p < FCT; p += 32) {
    float v = pv[p * 8 + b]; int id = pi[p * 8 + b];
    if (v > bv || (v == bv && id < bi)) { bv = v; bi = id; }
  }
  rv[tid] = bv; ri[tid] = bi;
  __syncthreads();
  for (int off = 128; off >= 8; off >>= 1) {
    if (tid < off) {
      float v = rv[tid + off]; int id = ri[tid + off];
      if (v > rv[tid] || (v == rv[tid] && id < ri[tid])) { rv[tid] = v; ri[tid] = id; }
    }
    __syncthreads();
  }
  if (tid < 8) tok[tid * 64 + t + 1] = ri[tid];
}

extern "C" void kernel_launch(void* const* d_in, const int* in_sizes, int n_in,
                              void* d_out, int out_size, void* d_ws, size_t ws_size,
                              hipStream_t stream) {
  (void)in_sizes; (void)n_in; (void)out_size; (void)ws_size;
  const float* embedding = (const float*)d_in[0];
  const float* w_proj   = (const float*)d_in[1];
  const float* b_proj   = (const float*)d_in[2];
  const float* tok_emb  = (const float*)d_in[3];
  const float* pos_enc  = (const float*)d_in[4];
  const float* sa_in_w  = (const float*)d_in[5];
  const float* sa_in_b  = (const float*)d_in[6];
  const float* sa_out_w = (const float*)d_in[7];
  const float* sa_out_b = (const float*)d_in[8];
  const float* ca_in_w  = (const float*)d_in[9];
  const float* ca_in_b  = (const float*)d_in[10];
  const float* ca_out_w = (const float*)d_in[11];
  const float* ca_out_b = (const float*)d_in[12];
  const float* ff1_w    = (const float*)d_in[13];
  const float* ff1_b    = (const float*)d_in[14];
  const float* ff2_w    = (const float*)d_in[15];
  const float* ff2_b    = (const float*)d_in[16];
  const float* ln_g     = (const float*)d_in[17];
  const float* ln_b     = (const float*)d_in[18];
  const float* fc_w     = (const float*)d_in[19];
  const float* fc_b     = (const float*)d_in[20];
  float* out = (float*)d_out;
  float* wsf = (float*)d_ws;
  int*   wsi = (int*)d_ws;

  // Decide cooperative viability fresh each call (host-only queries; capture-safe).
  int dev = 0;
  (void)hipGetDevice(&dev);
  int coopAttr = 0;
  (void)hipDeviceGetAttribute(&coopAttr, hipDeviceAttributeCooperativeLaunch, dev);
  int ncu = 0;
  (void)hipDeviceGetAttribute(&ncu, hipDeviceAttributeMultiprocessorCount, dev);
  int maxb = 0;
  hipError_t oe = hipOccupancyMaxActiveBlocksPerMultiprocessor(&maxb, k_persist, 256, 0);

  bool coop_ok = (coopAttr != 0) && (oe == hipSuccess) && ((long)maxb * (long)ncu >= NBLK);

  if (coop_ok) {
    void* args[] = {
        (void*)&embedding, (void*)&w_proj, (void*)&b_proj, (void*)&tok_emb, (void*)&pos_enc,
        (void*)&sa_in_w, (void*)&sa_in_b, (void*)&sa_out_w, (void*)&sa_out_b,
        (void*)&ca_in_w, (void*)&ca_in_b, (void*)&ca_out_w, (void*)&ca_out_b,
        (void*)&ff1_w, (void*)&ff1_b, (void*)&ff2_w, (void*)&ff2_b,
        (void*)&ln_g, (void*)&ln_b, (void*)&fc_w, (void*)&fc_b,
        (void*)&out, (void*)&wsf, (void*)&wsi};
    hipError_t le = hipLaunchCooperativeKernel((void*)k_persist, dim3(NBLK), dim3(256),
                                               args, 0, stream);
    if (le != hipSuccess) coop_ok = false;
  }

  if (!coop_ok) {
    // fallback: proven multi-kernel path
    float* mem = wsf + WS_MEM;
    float* ca  = wsf + WS_CA;
    float* x   = wsf + WS_X;
    float* q   = wsf + WS_Q;
    float* ffp = wsf + WS_FFP;
    float* kc  = wsf + WS_KC;
    float* vc  = wsf + WS_VC;
    float* pv  = wsf + WS_PV;
    int*   pi  = wsi + WS_PI;
    int*   tok = wsi + WS_TOK;

    k_mem<<<64, 256, 0, stream>>>(embedding, w_proj, b_proj, mem);
    k_ca<<<32, 256, 0, stream>>>(mem, ca_in_w, ca_in_b, ca_out_w, ca_out_b, ca);
    k_tok_init<<<1, 64, 0, stream>>>(tok);

    for (int t = 0; t < NSTEP; ++t) {
      k_embed<<<1, 256, 0, stream>>>(tok, tok_emb, pos_enc, x, t);
      for (int l = 0; l < NLAY; ++l) {
        k_qkv<<<24, 256, 0, stream>>>(x, sa_in_w, sa_in_b, q, kc, vc, l, t);
        k_attn<<<8, 256, 0, stream>>>(q, x, kc, vc, sa_out_w, sa_out_b, ln_g, ln_b, ca, l, t);
        k_ffn<<<32, 256, 0, stream>>>(x, ff1_w, ff1_b, ff2_w, ffp, l);
        k_ffred<<<8, 256, 0, stream>>>(x, ffp, ff2_b, ln_g, ln_b, l);
      }
      k_fc<<<FCT, 256, 0, stream>>>(x, fc_w, fc_b, out, pv, pi, t);
      k_amax<<<1, 256, 0, stream>>>(pv, pi, tok, t);
    }
  }
}

// Round 4
// 13656.541 us; speedup vs baseline: 2.5813x; 2.5813x over previous
//
#include <hip/hip_runtime.h>

#define NV 50257
#define BOSTOK 50256
#define LNEPS 1e-5f
#define NSTEP 49
#define NBLK 256
#define RPB 197          // fc rows per block: 256*197 = 50432 >= 50257
#define DYN_LDS_BYTES ((256 * 52 + 50 * 256) * 4)  // K (d-major, pitch 52) + V

// ---- flag word indices (unsigned, at start of d_ws; zeroed via hipMemsetAsync each call)
#define F_MEM 0
#define F_CA  1
#define F_QKV 2
#define F_XM  3
#define F_FFP 4
#define F_X   5
#define F_FC  6

// ---- float offsets in d_ws (flow path)
#define WS_MEM2  64
#define WS_CA2   2112
#define WS_XIN2  10304
#define WS_XMID2 12352
#define WS_XCUR2 14400
#define WS_Q2    16448
#define WS_KVS   18496   // [b][2][256] = 4096 floats
#define WS_FFP2  22592   // 65536
#define WS_PV2   88128   // 2048
#define WS_PI2   90176   // 2048 ints

// ---- fallback (round-1 proven) offsets
#define WS_MEM 0
#define WS_CA  2048
#define WS_X   10240
#define WS_Q   12288
#define WS_FFP 14336
#define WS_KC  79872
#define WS_VC  489472
#define WS_PV  899072
#define WS_PI  905472
#define WS_TOK 911872
#define FCT 786

// ================= LLC-coherent helpers (relaxed agent atomics: no L2 flushes) =================
__device__ __forceinline__ float gld(const float* p) {
  return __hip_atomic_load(const_cast<float*>(p), __ATOMIC_RELAXED, __HIP_MEMORY_SCOPE_AGENT);
}
__device__ __forceinline__ void gst(float* p, float v) {
  __hip_atomic_store(p, v, __ATOMIC_RELAXED, __HIP_MEMORY_SCOPE_AGENT);
}
__device__ __forceinline__ int gldi(const int* p) {
  return __hip_atomic_load(const_cast<int*>(p), __ATOMIC_RELAXED, __HIP_MEMORY_SCOPE_AGENT);
}
__device__ __forceinline__ void gsti(int* p, int v) {
  __hip_atomic_store(p, v, __ATOMIC_RELAXED, __HIP_MEMORY_SCOPE_AGENT);
}
// producer: every wave drains its global stores, block syncs, one thread bumps the flag
__device__ __forceinline__ void bump(unsigned* f) {
  asm volatile("s_waitcnt vmcnt(0)" ::: "memory");
  __syncthreads();
  if (threadIdx.x == 0)
    __hip_atomic_fetch_add(f, 1u, __ATOMIC_RELAXED, __HIP_MEMORY_SCOPE_AGENT);
}
// consumer: thread 0 spins (with sleep backoff), whole block released by syncthreads
__device__ __forceinline__ void waitf(unsigned* f, unsigned tgt) {
  if (threadIdx.x == 0) {
    while (__hip_atomic_load(f, __ATOMIC_RELAXED, __HIP_MEMORY_SCOPE_AGENT) < tgt)
      __builtin_amdgcn_s_sleep(2);
  }
  __syncthreads();
}

__device__ __forceinline__ float block_ln256(float v, int tid, float* red8, float g, float bta) {
  float s = v, s2 = v * v;
#pragma unroll
  for (int m = 32; m >= 1; m >>= 1) { s += __shfl_xor(s, m); s2 += __shfl_xor(s2, m); }
  int w = tid >> 6;
  __syncthreads();
  if ((tid & 63) == 0) { red8[w] = s; red8[4 + w] = s2; }
  __syncthreads();
  s = red8[0] + red8[1] + red8[2] + red8[3];
  s2 = red8[4] + red8[5] + red8[6] + red8[7];
  float mn = s * (1.0f / 256.0f);
  float var = s2 * (1.0f / 256.0f) - mn * mn;
  float rs = rsqrtf(var + LNEPS);
  return (v - mn) * rs * g + bta;
}

// ================= single-dispatch dataflow kernel =================
__global__ __launch_bounds__(256) void k_flow(
    const float* __restrict__ emb, const float* __restrict__ w_proj, const float* __restrict__ b_proj,
    const float* __restrict__ tok_emb, const float* __restrict__ pos_enc,
    const float* __restrict__ sa_in_w, const float* __restrict__ sa_in_b,
    const float* __restrict__ sa_out_w, const float* __restrict__ sa_out_b,
    const float* __restrict__ ca_in_w, const float* __restrict__ ca_in_b,
    const float* __restrict__ ca_out_w, const float* __restrict__ ca_out_b,
    const float* __restrict__ ff1_w, const float* __restrict__ ff1_b,
    const float* __restrict__ ff2_w, const float* __restrict__ ff2_b,
    const float* __restrict__ ln_g, const float* __restrict__ ln_b,
    const float* __restrict__ fc_w, const float* __restrict__ fc_b,
    float* __restrict__ out, float* __restrict__ wsf, int* __restrict__ wsi) {
  extern __shared__ float dynlds[];   // B-role: persistent K (256*52) + V (50*256)
  const int bid = blockIdx.x, tid = threadIdx.x;

  unsigned* flags = (unsigned*)wsf;
  unsigned* fmem = flags + F_MEM; unsigned* fca = flags + F_CA;
  unsigned* fqkv = flags + F_QKV; unsigned* fxm = flags + F_XM;
  unsigned* fffp = flags + F_FFP; unsigned* fx = flags + F_X;
  unsigned* ffc = flags + F_FC;

  float* mem  = wsf + WS_MEM2;
  float* ca   = wsf + WS_CA2;
  float* xin  = wsf + WS_XIN2;
  float* xmid = wsf + WS_XMID2;
  float* xcur = wsf + WS_XCUR2;
  float* qb   = wsf + WS_Q2;
  float* kvs  = wsf + WS_KVS;
  float* ffp  = wsf + WS_FFP2;
  float* pv   = wsf + WS_PV2;
  int*   pi   = wsi + WS_PI2;

  __shared__ float xl[8 * 260];
  __shared__ float h1l[64 * 9];
  __shared__ float ql[256], ol[256], ph[8 * 64];
  __shared__ float red8[8];
  __shared__ float rv[256];
  __shared__ int   ri[256];
  __shared__ int   toks[8];
  __shared__ float el[1536];

  // ---- init 1: mem = embedding @ w_proj.T + b_proj (blocks 0..63)
  if (bid < 64) {
    int b = bid >> 3, tile = bid & 7;
    for (int k = tid; k < 1536; k += 256) el[k] = emb[b * 1536 + k];
    __syncthreads();
    int r = tid >> 3, g = tid & 7;
    int row = tile * 32 + r;
    float acc = 0.f;
    const float* wr = w_proj + (size_t)row * 1536;
    for (int c = g * 192; c < g * 192 + 192; ++c) acc += wr[c] * el[c];
    rv[tid] = acc;
    __syncthreads();
    for (int off = 4; off >= 1; off >>= 1) {
      if (g < off) rv[tid] += rv[tid + off];
      __syncthreads();
    }
    if (g == 0) gst(mem + b * 256 + row, rv[tid] + b_proj[row]);
    bump(fmem);
  }
  // ---- init 2: cross-attn constant (memory len 1 => attn == V_mem) (blocks 0..31)
  if (bid < 32) {
    waitf(fmem, 64u);
    int l = bid >> 3, b = bid & 7;
    ql[tid] = gld(mem + b * 256 + tid);
    __syncthreads();
    float acc = ca_in_b[l * 768 + 512 + tid];
    const float* wr = ca_in_w + (size_t)(l * 768 + 512 + tid) * 256;
    for (int c = 0; c < 256; ++c) acc += wr[c] * ql[c];
    ol[tid] = acc;
    __syncthreads();
    float acc2 = ca_out_b[l * 256 + tid];
    const float* wr2 = ca_out_w + (size_t)(l * 256 + tid) * 256;
    for (int c = 0; c < 256; ++c) acc2 += wr2[c] * ol[c];
    gst(ca + (l * 8 + b) * 256 + tid, acc2);
    bump(fca);
  }

  if (bid < 24) {
    // ========== A-role: prologue + QKV GEMV; blocks 0..7 also produce x and xfin ==========
    for (int t = 0; t < NSTEP; ++t) {
      for (int l = 0; l < 4; ++l) {
        if (l == 0) {
          if (t == 0) {
            if (tid < 8) toks[tid] = BOSTOK;
            __syncthreads();
          } else {
            waitf(ffc, 256u * (unsigned)t);
            int b = tid & 7, i0 = tid >> 3;
            float bv = -3e38f; int bi = 2147483647;
            for (int p = i0; p < NBLK; p += 32) {
              float v = gld(pv + p * 8 + b); int id = gldi(pi + p * 8 + b);
              if (v > bv || (v == bv && id < bi)) { bv = v; bi = id; }
            }
            rv[tid] = bv; ri[tid] = bi;
            __syncthreads();
            for (int off = 128; off >= 8; off >>= 1) {
              if (tid < off) {
                float v = rv[tid + off]; int id = ri[tid + off];
                if (v > rv[tid] || (v == rv[tid] && id < ri[tid])) { rv[tid] = v; ri[tid] = id; }
              }
              __syncthreads();
            }
            if (tid < 8) toks[tid] = ri[tid];
            __syncthreads();
          }
          for (int b = 0; b < 8; ++b)
            xl[b * 260 + tid] = tok_emb[(size_t)toks[b] * 256 + tid] + pos_enc[t * 256 + tid];
          __syncthreads();
        } else {
          if (bid < 8) {  // produce x^{l} from FFN(l-1)
            waitf(fffp, 32u * (unsigned)(4 * t + l));
            int b = bid;
            float a = gld(xmid + b * 256 + tid) + ff2_b[(l - 1) * 256 + tid];
            for (int s = 0; s < 32; ++s) a += gld(ffp + (s * 8 + b) * 256 + tid);
            float y = block_ln256(a, tid, red8, ln_g[((l - 1) * 3 + 2) * 256 + tid],
                                  ln_b[((l - 1) * 3 + 2) * 256 + tid]);
            gst(xcur + b * 256 + tid, y);
            bump(fx);
          }
          waitf(fx, 8u * (unsigned)(4 * t + l));
          for (int b = 0; b < 8; ++b) xl[b * 260 + tid] = gld(xcur + b * 256 + tid);
          __syncthreads();
        }
        if (bid < 8) gst(xin + bid * 256 + tid, xl[bid * 260 + tid]);
        // QKV GEMV: rows bid*32 .. +32
        int r = tid >> 3, b8 = tid & 7;
        int row = bid * 32 + r;
        float acc = sa_in_b[l * 768 + row];
        const float4* w4 = reinterpret_cast<const float4*>(sa_in_w + (size_t)(l * 768 + row) * 256);
        const float4* xv = reinterpret_cast<const float4*>(xl + b8 * 260);
#pragma unroll 8
        for (int k = 0; k < 64; ++k) {
          float4 wv = w4[k]; float4 xq = xv[k];
          acc += wv.x * xq.x + wv.y * xq.y + wv.z * xq.z + wv.w * xq.w;
        }
        if (row < 256) gst(qb + b8 * 256 + row, acc);
        else if (row < 512) gst(kvs + b8 * 512 + (row - 256), acc);
        else gst(kvs + b8 * 512 + 256 + (row - 512), acc);
        bump(fqkv);
      }  // l
      // final hidden: blocks 0..7 produce xfin -> xcur
      if (bid < 8) {
        waitf(fffp, 32u * (unsigned)(4 * t + 4));
        int b = bid;
        float a = gld(xmid + b * 256 + tid) + ff2_b[3 * 256 + tid];
        for (int s = 0; s < 32; ++s) a += gld(ffp + (s * 8 + b) * 256 + tid);
        float y = block_ln256(a, tid, red8, ln_g[(3 * 3 + 2) * 256 + tid],
                              ln_b[(3 * 3 + 2) * 256 + tid]);
        gst(xcur + b * 256 + tid, y);
        bump(fx);
      }
      goto do_fc_a;  // fall through to shared fc code below via common path
    do_fc_a:;
      // ---- fc phase (same for all roles) ----
      {
        waitf(fx, 8u * (unsigned)(4 * t + 4));
        for (int b = 0; b < 8; ++b) xl[b * 260 + tid] = gld(xcur + b * 256 + tid);
        __syncthreads();
        int rr0 = tid >> 3, b = tid & 7;
        float bv = -3e38f; int bi = 2147483647;
        int base = bid * RPB;
        for (int i = 0; i < 7; ++i) {
          int rr = i * 32 + rr0, row = base + rr;
          if (rr < RPB && row < NV) {
            float acc = fc_b[row];
            const float4* w4 = reinterpret_cast<const float4*>(fc_w + (size_t)row * 256);
            const float4* xv = reinterpret_cast<const float4*>(xl + b * 260);
            for (int k = 0; k < 64; ++k) {
              float4 wv = w4[k]; float4 xq = xv[k];
              acc += wv.x * xq.x + wv.y * xq.y + wv.z * xq.z + wv.w * xq.w;
            }
            out[(size_t)(b * 49 + t) * NV + row] = acc;
            if (acc > bv || (acc == bv && row < bi)) { bv = acc; bi = row; }
          }
        }
        rv[tid] = bv; ri[tid] = bi;
        __syncthreads();
        for (int off = 128; off >= 8; off >>= 1) {
          if (tid < off) {
            float v = rv[tid + off]; int id = ri[tid + off];
            if (v > rv[tid] || (v == rv[tid] && id < ri[tid])) { rv[tid] = v; ri[tid] = id; }
          }
          __syncthreads();
        }
        if (tid < 8) { gst(pv + bid * 8 + tid, rv[tid]); gsti(pi + bid * 8 + tid, ri[tid]); }
        bump(ffc);
      }
    }  // t
  } else if (bid < 56) {
    // ========== B-role: attention owner for (myl, myb); K/V history in LDS ==========
    int myl = (bid - 24) >> 3, myb = (bid - 24) & 7;
    float* Klds = dynlds;             // [256][52] d-major: K[h*32+d][j]
    float* Vlds = dynlds + 256 * 52;  // [50][256]
    waitf(fca, 32u);
    for (int t = 0; t < NSTEP; ++t) {
      waitf(fqkv, 24u * (unsigned)(4 * t + myl + 1));
      // append new K/V column
      Klds[tid * 52 + t] = gld(kvs + myb * 512 + tid);
      Vlds[t * 256 + tid] = gld(kvs + myb * 512 + 256 + tid);
      ql[tid] = gld(qb + myb * 256 + tid);
      float xres = gld(xin + myb * 256 + tid);
      __syncthreads();
      int h = tid >> 5, j0 = tid & 31;
      const float* qh = ql + h * 32;
      float s0 = -3e38f, s1 = -3e38f;
      if (j0 <= t) {
        float d0 = 0.f;
#pragma unroll
        for (int d = 0; d < 32; ++d) d0 += qh[d] * Klds[(h * 32 + d) * 52 + j0];
        s0 = d0 * 0.17677669529663687f;
      }
      if (j0 + 32 <= t) {
        float d1 = 0.f;
#pragma unroll
        for (int d = 0; d < 32; ++d) d1 += qh[d] * Klds[(h * 32 + d) * 52 + j0 + 32];
        s1 = d1 * 0.17677669529663687f;
      }
      float mx = fmaxf(s0, s1);
      for (int m = 16; m >= 1; m >>= 1) mx = fmaxf(mx, __shfl_xor(mx, m, 32));
      float e0 = (j0 <= t) ? expf(s0 - mx) : 0.f;
      float e1 = (j0 + 32 <= t) ? expf(s1 - mx) : 0.f;
      float sm = e0 + e1;
      for (int m = 16; m >= 1; m >>= 1) sm += __shfl_xor(sm, m, 32);
      ph[h * 64 + j0] = e0;
      ph[h * 64 + j0 + 32] = e1;
      __syncthreads();
      float o = 0.f;
      for (int j = 0; j <= t; ++j) o += ph[h * 64 + j] * Vlds[j * 256 + tid];
      ol[tid] = o / sm;
      __syncthreads();
      // out-proj + residual + LN1 + ca + LN2
      float acc = sa_out_b[myl * 256 + tid];
      const float4* w4 = reinterpret_cast<const float4*>(sa_out_w + (size_t)(myl * 256 + tid) * 256);
#pragma unroll 4
      for (int k = 0; k < 64; ++k) {
        float4 wv = w4[k];
        acc += wv.x * ol[4 * k] + wv.y * ol[4 * k + 1] + wv.z * ol[4 * k + 2] + wv.w * ol[4 * k + 3];
      }
      acc += xres;
      float y = block_ln256(acc, tid, red8, ln_g[(myl * 3 + 0) * 256 + tid],
                            ln_b[(myl * 3 + 0) * 256 + tid]);
      float acc2 = y + gld(ca + (myl * 8 + myb) * 256 + tid);
      float y2 = block_ln256(acc2, tid, red8, ln_g[(myl * 3 + 1) * 256 + tid],
                             ln_b[(myl * 3 + 1) * 256 + tid]);
      gst(xmid + myb * 256 + tid, y2);
      bump(fxm);
      // ---- fc phase ----
      {
        waitf(fx, 8u * (unsigned)(4 * t + 4));
        for (int b = 0; b < 8; ++b) xl[b * 260 + tid] = gld(xcur + b * 256 + tid);
        __syncthreads();
        int rr0 = tid >> 3, b = tid & 7;
        float bv = -3e38f; int bi = 2147483647;
        int base = bid * RPB;
        for (int i = 0; i < 7; ++i) {
          int rr = i * 32 + rr0, row = base + rr;
          if (rr < RPB && row < NV) {
            float acc2b = fc_b[row];
            const float4* w4b = reinterpret_cast<const float4*>(fc_w + (size_t)row * 256);
            const float4* xvb = reinterpret_cast<const float4*>(xl + b * 260);
            for (int k = 0; k < 64; ++k) {
              float4 wv = w4b[k]; float4 xq = xvb[k];
              acc2b += wv.x * xq.x + wv.y * xq.y + wv.z * xq.z + wv.w * xq.w;
            }
            out[(size_t)(b * 49 + t) * NV + row] = acc2b;
            if (acc2b > bv || (acc2b == bv && row < bi)) { bv = acc2b; bi = row; }
          }
        }
        rv[tid] = bv; ri[tid] = bi;
        __syncthreads();
        for (int off = 128; off >= 8; off >>= 1) {
          if (tid < off) {
            float v = rv[tid + off]; int id = ri[tid + off];
            if (v > rv[tid] || (v == rv[tid] && id < ri[tid])) { rv[tid] = v; ri[tid] = id; }
          }
          __syncthreads();
        }
        if (tid < 8) { gst(pv + bid * 8 + tid, rv[tid]); gsti(pi + bid * 8 + tid, ri[tid]); }
        bump(ffc);
      }
    }
  } else {
    // ========== C-role (56..87): FFN slices; others (88..255): fc only ==========
    int s = bid - 56;
    bool cact = (s >= 0 && s < 32);
    for (int t = 0; t < NSTEP; ++t) {
      if (cact) {
        for (int l = 0; l < 4; ++l) {
          waitf(fxm, 8u * (unsigned)(4 * t + l + 1));
          for (int b = 0; b < 8; ++b) xl[b * 260 + tid] = gld(xmid + b * 256 + tid);
          __syncthreads();
          int n0 = tid >> 3, b = tid & 7;
#pragma unroll
          for (int i = 0; i < 2; ++i) {
            int nn = n0 + i * 32, row = s * 64 + nn;
            float acc = ff1_b[l * 2048 + row];
            const float4* w4 = reinterpret_cast<const float4*>(ff1_w + (size_t)(l * 2048 + row) * 256);
            const float4* xv = reinterpret_cast<const float4*>(xl + b * 260);
            for (int k = 0; k < 64; ++k) {
              float4 wv = w4[k]; float4 xq = xv[k];
              acc += wv.x * xq.x + wv.y * xq.y + wv.z * xq.z + wv.w * xq.w;
            }
            h1l[nn * 9 + b] = fmaxf(acc, 0.f);
          }
          __syncthreads();
          float facc[8] = {0, 0, 0, 0, 0, 0, 0, 0};
          const float* w2p = ff2_w + (size_t)(l * 256 + tid) * 2048 + s * 64;
          for (int n = 0; n < 64; ++n) {
            float wv = w2p[n];
#pragma unroll
            for (int b2 = 0; b2 < 8; ++b2) facc[b2] += wv * h1l[n * 9 + b2];
          }
          for (int b2 = 0; b2 < 8; ++b2) gst(ffp + (s * 8 + b2) * 256 + tid, facc[b2]);
          bump(fffp);
        }
      }
      // ---- fc phase ----
      {
        waitf(fx, 8u * (unsigned)(4 * t + 4));
        for (int b = 0; b < 8; ++b) xl[b * 260 + tid] = gld(xcur + b * 256 + tid);
        __syncthreads();
        int rr0 = tid >> 3, b = tid & 7;
        float bv = -3e38f; int bi = 2147483647;
        int base = bid * RPB;
        for (int i = 0; i < 7; ++i) {
          int rr = i * 32 + rr0, row = base + rr;
          if (rr < RPB && row < NV) {
            float acc = fc_b[row];
            const float4* w4 = reinterpret_cast<const float4*>(fc_w + (size_t)row * 256);
            const float4* xv = reinterpret_cast<const float4*>(xl + b * 260);
            for (int k = 0; k < 64; ++k) {
              float4 wv = w4[k]; float4 xq = xv[k];
              acc += wv.x * xq.x + wv.y * xq.y + wv.z * xq.z + wv.w * xq.w;
            }
            out[(size_t)(b * 49 + t) * NV + row] = acc;
            if (acc > bv || (acc == bv && row < bi)) { bv = acc; bi = row; }
          }
        }
        rv[tid] = bv; ri[tid] = bi;
        __syncthreads();
        for (int off = 128; off >= 8; off >>= 1) {
          if (tid < off) {
            float v = rv[tid + off]; int id = ri[tid + off];
            if (v > rv[tid] || (v == rv[tid] && id < ri[tid])) { rv[tid] = v; ri[tid] = id; }
          }
          __syncthreads();
        }
        if (tid < 8) { gst(pv + bid * 8 + tid, rv[tid]); gsti(pi + bid * 8 + tid, ri[tid]); }
        bump(ffc);
      }
    }
  }
}

// ================= fallback path (round-1, proven at 13.7 ms) =================
__device__ __forceinline__ float block_ln(float v, int tid, float* red, float* red2,
                                          float g, float bta) {
  red[tid] = v; red2[tid] = v * v;
  __syncthreads();
  for (int off = 128; off > 0; off >>= 1) {
    if (tid < off) { red[tid] += red[tid + off]; red2[tid] += red2[tid + off]; }
    __syncthreads();
  }
  float m = red[0] * (1.0f / 256.0f);
  float var = red2[0] * (1.0f / 256.0f) - m * m;
  float rs = rsqrtf(var + LNEPS);
  float y = (v - m) * rs * g + bta;
  __syncthreads();
  return y;
}

__global__ __launch_bounds__(256) void k_mem(const float* __restrict__ emb,
                                             const float* __restrict__ w,
                                             const float* __restrict__ bias,
                                             float* __restrict__ mem) {
  __shared__ float el[1536];
  __shared__ float red[256];
  int b = blockIdx.x >> 3, tile = blockIdx.x & 7, tid = threadIdx.x;
  for (int k = tid; k < 1536; k += 256) el[k] = emb[b * 1536 + k];
  __syncthreads();
  int r = tid >> 3, g = tid & 7;
  int row = tile * 32 + r;
  float acc = 0.f;
  const float* wr = w + row * 1536;
  for (int c = g * 192; c < g * 192 + 192; ++c) acc += wr[c] * el[c];
  red[tid] = acc;
  __syncthreads();
  for (int off = 4; off >= 1; off >>= 1) {
    if (g < off) red[tid] += red[tid + off];
    __syncthreads();
  }
  if (g == 0) mem[b * 256 + row] = red[tid] + bias[row];
}

__global__ __launch_bounds__(256) void k_ca(const float* __restrict__ mem,
                                            const float* __restrict__ iw,
                                            const float* __restrict__ ib,
                                            const float* __restrict__ ow,
                                            const float* __restrict__ ob,
                                            float* __restrict__ ca) {
  __shared__ float ml[256], vl[256];
  int l = blockIdx.x >> 3, b = blockIdx.x & 7, tid = threadIdx.x;
  ml[tid] = mem[b * 256 + tid];
  __syncthreads();
  float acc = ib[l * 768 + 512 + tid];
  const float* wr = iw + (size_t)(l * 768 + 512 + tid) * 256;
  for (int c = 0; c < 256; ++c) acc += wr[c] * ml[c];
  vl[tid] = acc;
  __syncthreads();
  float acc2 = ob[l * 256 + tid];
  const float* wr2 = ow + (size_t)(l * 256 + tid) * 256;
  for (int c = 0; c < 256; ++c) acc2 += wr2[c] * vl[c];
  ca[(l * 8 + b) * 256 + tid] = acc2;
}

__global__ void k_tok_init(int* __restrict__ tok) {
  if (threadIdx.x < 8) tok[threadIdx.x * 64] = BOSTOK;
}

__global__ __launch_bounds__(256) void k_embed(const int* __restrict__ tok,
                                               const float* __restrict__ te,
                                               const float* __restrict__ pe,
                                               float* __restrict__ x, int t) {
  int tid = threadIdx.x;
  for (int b = 0; b < 8; ++b) {
    int tk = tok[b * 64 + t];
    x[b * 256 + tid] = te[(size_t)tk * 256 + tid] + pe[t * 256 + tid];
  }
}

__global__ __launch_bounds__(256) void k_qkv(const float* __restrict__ x,
                                             const float* __restrict__ w,
                                             const float* __restrict__ bias,
                                             float* __restrict__ q,
                                             float* __restrict__ kc,
                                             float* __restrict__ vc, int l, int t) {
  __shared__ float xl[8 * 260];
  int tid = threadIdx.x;
  for (int k = 0; k < 8; ++k) {
    int idx = tid + k * 256;
    xl[(idx >> 8) * 260 + (idx & 255)] = x[idx];
  }
  __syncthreads();
  int r = tid >> 3, b = tid & 7;
  int row = blockIdx.x * 32 + r;
  float acc = bias[l * 768 + row];
  const float4* w4 = reinterpret_cast<const float4*>(w + (size_t)(l * 768 + row) * 256);
  const float4* xv = reinterpret_cast<const float4*>(xl + b * 260);
#pragma unroll 8
  for (int k = 0; k < 64; ++k) {
    float4 wv = w4[k]; float4 xq = xv[k];
    acc += wv.x * xq.x + wv.y * xq.y + wv.z * xq.z + wv.w * xq.w;
  }
  if (row < 256) {
    q[b * 256 + row] = acc;
  } else if (row < 512) {
    int h = (row - 256) >> 5, d = (row - 256) & 31;
    kc[(((l * 8 + b) * 8 + h) * 50 + t) * 32 + d] = acc;
  } else {
    int h = (row - 512) >> 5, d = (row - 512) & 31;
    vc[(((l * 8 + b) * 8 + h) * 50 + t) * 32 + d] = acc;
  }
}

__global__ __launch_bounds__(256) void k_attn(const float* __restrict__ q,
                                              float* __restrict__ x,
                                              const float* __restrict__ kc,
                                              const float* __restrict__ vc,
                                              const float* __restrict__ ow,
                                              const float* __restrict__ ob,
                                              const float* __restrict__ lg,
                                              const float* __restrict__ lb,
                                              const float* __restrict__ ca, int l, int t) {
  __shared__ float ql[256], ol[256], sc[64], red[256], red2[256];
  __shared__ float ssum;
  int b = blockIdx.x, tid = threadIdx.x;
  float xres = x[b * 256 + tid];
  ql[tid] = q[b * 256 + tid];
  __syncthreads();
  for (int h = 0; h < 8; ++h) {
    const float* kb = kc + (size_t)(((l * 8 + b) * 8 + h) * 50) * 32;
    if (tid <= t) {
      float s = 0.f;
      const float* kr = kb + tid * 32;
#pragma unroll
      for (int d = 0; d < 32; ++d) s += ql[h * 32 + d] * kr[d];
      sc[tid] = s * 0.17677669529663687f;
    }
    __syncthreads();
    if (tid < 64) {
      float v = (tid <= t) ? sc[tid] : -1e30f;
      float mx = v;
      for (int m = 32; m >= 1; m >>= 1) mx = fmaxf(mx, __shfl_xor(mx, m));
      float e = (tid <= t) ? expf(sc[tid] - mx) : 0.f;
      sc[tid] = e;
      float sm = e;
      for (int m = 32; m >= 1; m >>= 1) sm += __shfl_xor(sm, m);
      if (tid == 0) ssum = sm;
    }
    __syncthreads();
    if (tid < 32) {
      const float* vb = vc + (size_t)(((l * 8 + b) * 8 + h) * 50) * 32 + tid;
      float acc = 0.f;
      for (int j = 0; j <= t; ++j) acc += sc[j] * vb[j * 32];
      ol[h * 32 + tid] = acc / ssum;
    }
    __syncthreads();
  }
  float acc = ob[l * 256 + tid];
  const float4* w4 = reinterpret_cast<const float4*>(ow + (size_t)(l * 256 + tid) * 256);
#pragma unroll 4
  for (int k = 0; k < 64; ++k) {
    float4 wv = w4[k];
    acc += wv.x * ol[4 * k] + wv.y * ol[4 * k + 1] + wv.z * ol[4 * k + 2] + wv.w * ol[4 * k + 3];
  }
  acc += xres;
  float y = block_ln(acc, tid, red, red2, lg[(l * 3 + 0) * 256 + tid], lb[(l * 3 + 0) * 256 + tid]);
  float acc2 = y + ca[(l * 8 + b) * 256 + tid];
  float y2 = block_ln(acc2, tid, red, red2, lg[(l * 3 + 1) * 256 + tid], lb[(l * 3 + 1) * 256 + tid]);
  x[b * 256 + tid] = y2;
}

__global__ __launch_bounds__(256) void k_ffn(const float* __restrict__ x,
                                             const float* __restrict__ w1,
                                             const float* __restrict__ b1,
                                             const float* __restrict__ w2,
                                             float* __restrict__ ffp, int l) {
  __shared__ float xl[8 * 260];
  __shared__ float h1l[64 * 9];
  int tid = threadIdx.x, s = blockIdx.x;
  for (int k = 0; k < 8; ++k) {
    int idx = tid + k * 256;
    xl[(idx >> 8) * 260 + (idx & 255)] = x[idx];
  }
  __syncthreads();
  int n0 = tid >> 3, b = tid & 7;
#pragma unroll
  for (int i = 0; i < 2; ++i) {
    int nn = n0 + i * 32, row = s * 64 + nn;
    float acc = b1[l * 2048 + row];
    const float4* w4 = reinterpret_cast<const float4*>(w1 + (size_t)(l * 2048 + row) * 256);
    const float4* xv = reinterpret_cast<const float4*>(xl + b * 260);
    for (int k = 0; k < 64; ++k) {
      float4 wv = w4[k]; float4 xq = xv[k];
      acc += wv.x * xq.x + wv.y * xq.y + wv.z * xq.z + wv.w * xq.w;
    }
    h1l[nn * 9 + b] = fmaxf(acc, 0.f);
  }
  __syncthreads();
  int row = tid;
  float acc[8] = {0, 0, 0, 0, 0, 0, 0, 0};
  const float* w2p = w2 + (size_t)(l * 256 + row) * 2048 + s * 64;
  for (int n = 0; n < 64; ++n) {
    float wv = w2p[n];
#pragma unroll
    for (int b2 = 0; b2 < 8; ++b2) acc[b2] += wv * h1l[n * 9 + b2];
  }
  for (int b2 = 0; b2 < 8; ++b2) ffp[(s * 8 + b2) * 256 + row] = acc[b2];
}

__global__ __launch_bounds__(256) void k_ffred(float* __restrict__ x,
                                               const float* __restrict__ ffp,
                                               const float* __restrict__ b2,
                                               const float* __restrict__ lg,
                                               const float* __restrict__ lb, int l) {
  __shared__ float red[256], red2[256];
  int b = blockIdx.x, tid = threadIdx.x;
  float acc = b2[l * 256 + tid] + x[b * 256 + tid];
  for (int s = 0; s < 32; ++s) acc += ffp[(s * 8 + b) * 256 + tid];
  float y = block_ln(acc, tid, red, red2, lg[(l * 3 + 2) * 256 + tid], lb[(l * 3 + 2) * 256 + tid]);
  x[b * 256 + tid] = y;
}

__global__ __launch_bounds__(256) void k_fc(const float* __restrict__ h,
                                            const float* __restrict__ w,
                                            const float* __restrict__ bias,
                                            float* __restrict__ out,
                                            float* __restrict__ pv,
                                            int* __restrict__ pi, int t) {
  __shared__ float hl[8 * 260];
  __shared__ float rv[256];
  __shared__ int ri[256];
  int tid = threadIdx.x, wg = blockIdx.x;
  for (int k = 0; k < 8; ++k) {
    int idx = tid + k * 256;
    hl[(idx >> 8) * 260 + (idx & 255)] = h[idx];
  }
  __syncthreads();
  int r = tid >> 3, b = tid & 7;
  float bv = -3e38f;
  int bi = 2147483647;
  for (int i = 0; i < 2; ++i) {
    int row = wg * 64 + i * 32 + r;
    if (row < NV) {
      float acc = bias[row];
      const float4* w4 = reinterpret_cast<const float4*>(w + (size_t)row * 256);
      const float4* xv = reinterpret_cast<const float4*>(hl + b * 260);
      for (int k = 0; k < 64; ++k) {
        float4 wv = w4[k]; float4 xq = xv[k];
        acc += wv.x * xq.x + wv.y * xq.y + wv.z * xq.z + wv.w * xq.w;
      }
      out[(size_t)(b * 49 + t) * NV + row] = acc;
      if (acc > bv || (acc == bv && row < bi)) { bv = acc; bi = row; }
    }
  }
  rv[tid] = bv; ri[tid] = bi;
  __syncthreads();
  for (int off = 128; off >= 8; off >>= 1) {
    if (tid < off) {
      float v = rv[tid + off]; int id = ri[tid + off];
      if (v > rv[tid] || (v == rv[tid] && id < ri[tid])) { rv[tid] = v; ri[tid] = id; }
    }
    __syncthreads();
  }
  if (tid < 8) { pv[wg * 8 + tid] = rv[tid]; pi[wg * 8 + tid] = ri[tid]; }
}

__global__ __launch_bounds__(256) void k_amax(const float* __restrict__ pv,
                                              const int* __restrict__ pi,
                                              int* __restrict__ tok, int t) {
  __shared__ float rv[256];
  __shared__ int ri[256];
  int tid = threadIdx.x, b = tid & 7, i0 = tid >> 3;
  float bv = -3e38f;
  int bi = 2147483647;
  for (int p = i0; p < FCT; p += 32) {
    float v = pv[p * 8 + b]; int id = pi[p * 8 + b];
    if (v > bv || (v == bv && id < bi)) { bv = v; bi = id; }
  }
  rv[tid] = bv; ri[tid] = bi;
  __syncthreads();
  for (int off = 128; off >= 8; off >>= 1) {
    if (tid < off) {
      float v = rv[tid + off]; int id = ri[tid + off];
      if (v > rv[tid] || (v == rv[tid] && id < ri[tid])) { rv[tid] = v; ri[tid] = id; }
    }
    __syncthreads();
  }
  if (tid < 8) tok[tid * 64 + t + 1] = ri[tid];
}

extern "C" void kernel_launch(void* const* d_in, const int* in_sizes, int n_in,
                              void* d_out, int out_size, void* d_ws, size_t ws_size,
                              hipStream_t stream) {
  (void)in_sizes; (void)n_in; (void)out_size; (void)ws_size;
  const float* embedding = (const float*)d_in[0];
  const float* w_proj   = (const float*)d_in[1];
  const float* b_proj   = (const float*)d_in[2];
  const float* tok_emb  = (const float*)d_in[3];
  const float* pos_enc  = (const float*)d_in[4];
  const float* sa_in_w  = (const float*)d_in[5];
  const float* sa_in_b  = (const float*)d_in[6];
  const float* sa_out_w = (const float*)d_in[7];
  const float* sa_out_b = (const float*)d_in[8];
  const float* ca_in_w  = (const float*)d_in[9];
  const float* ca_in_b  = (const float*)d_in[10];
  const float* ca_out_w = (const float*)d_in[11];
  const float* ca_out_b = (const float*)d_in[12];
  const float* ff1_w    = (const float*)d_in[13];
  const float* ff1_b    = (const float*)d_in[14];
  const float* ff2_w    = (const float*)d_in[15];
  const float* ff2_b    = (const float*)d_in[16];
  const float* ln_g     = (const float*)d_in[17];
  const float* ln_b     = (const float*)d_in[18];
  const float* fc_w     = (const float*)d_in[19];
  const float* fc_b     = (const float*)d_in[20];
  float* out = (float*)d_out;
  float* wsf = (float*)d_ws;
  int*   wsi = (int*)d_ws;

  int dev = 0;
  (void)hipGetDevice(&dev);
  int coopAttr = 0;
  (void)hipDeviceGetAttribute(&coopAttr, hipDeviceAttributeCooperativeLaunch, dev);
  int ncu = 0;
  (void)hipDeviceGetAttribute(&ncu, hipDeviceAttributeMultiprocessorCount, dev);
  (void)hipFuncSetAttribute(reinterpret_cast<const void*>(k_flow),
                            hipFuncAttributeMaxDynamicSharedMemorySize, DYN_LDS_BYTES);
  int maxb = 0;
  hipError_t oe = hipOccupancyMaxActiveBlocksPerMultiprocessor(&maxb, k_flow, 256, DYN_LDS_BYTES);

  bool coop_ok = (coopAttr != 0) && (oe == hipSuccess) && ((long)maxb * (long)ncu >= NBLK);

  if (coop_ok) {
    // zero the flag words (deterministic per call; capture-safe async op)
    (void)hipMemsetAsync(d_ws, 0, 256, stream);
    void* args[] = {
        (void*)&embedding, (void*)&w_proj, (void*)&b_proj, (void*)&tok_emb, (void*)&pos_enc,
        (void*)&sa_in_w, (void*)&sa_in_b, (void*)&sa_out_w, (void*)&sa_out_b,
        (void*)&ca_in_w, (void*)&ca_in_b, (void*)&ca_out_w, (void*)&ca_out_b,
        (void*)&ff1_w, (void*)&ff1_b, (void*)&ff2_w, (void*)&ff2_b,
        (void*)&ln_g, (void*)&ln_b, (void*)&fc_w, (void*)&fc_b,
        (void*)&out, (void*)&wsf, (void*)&wsi};
    hipError_t le = hipLaunchCooperativeKernel((void*)k_flow, dim3(NBLK), dim3(256),
                                               args, DYN_LDS_BYTES, stream);
    if (le != hipSuccess) coop_ok = false;
  }

  if (!coop_ok) {
    float* mem = wsf + WS_MEM;
    float* ca  = wsf + WS_CA;
    float* x   = wsf + WS_X;
    float* q   = wsf + WS_Q;
    float* ffp = wsf + WS_FFP;
    float* kc  = wsf + WS_KC;
    float* vc  = wsf + WS_VC;
    float* pv  = wsf + WS_PV;
    int*   pi  = wsi + WS_PI;
    int*   tok = wsi + WS_TOK;

    k_mem<<<64, 256, 0, stream>>>(embedding, w_proj, b_proj, mem);
    k_ca<<<32, 256, 0, stream>>>(mem, ca_in_w, ca_in_b, ca_out_w, ca_out_b, ca);
    k_tok_init<<<1, 64, 0, stream>>>(tok);

    for (int t = 0; t < NSTEP; ++t) {
      k_embed<<<1, 256, 0, stream>>>(tok, tok_emb, pos_enc, x, t);
      for (int l = 0; l < 4; ++l) {
        k_qkv<<<24, 256, 0, stream>>>(x, sa_in_w, sa_in_b, q, kc, vc, l, t);
        k_attn<<<8, 256, 0, stream>>>(q, x, kc, vc, sa_out_w, sa_out_b, ln_g, ln_b, ca, l, t);
        k_ffn<<<32, 256, 0, stream>>>(x, ff1_w, ff1_b, ff2_w, ffp, l);
        k_ffred<<<8, 256, 0, stream>>>(x, ffp, ff2_b, ln_g, ln_b, l);
      }
      k_fc<<<FCT, 256, 0, stream>>>(x, fc_w, fc_b, out, pv, pi, t);
      k_amax<<<1, 256, 0, stream>>>(pv, pi, tok, t);
    }
  }
}

// Round 5
// 13628.412 us; speedup vs baseline: 2.5866x; 1.0021x over previous
//
#include <hip/hip_runtime.h>

#define NV 50257
#define BOSTOK 50256
#define LNEPS 1e-5f
#define NSTEP 49
#define NBLK 256
#define RPB 197          // fc rows per block: 256*197 = 50432 >= 50257
#define DYN_LDS_BYTES ((256 * 52 + 50 * 256) * 4)  // K (d-major, pitch 52) + V
#define FSTRIDE 64       // one flag per 256B line

// flag line indices
#define FL_FU(l)  (0 + (l))    // owner(l) published u: +8/step
#define FL_FP(l)  (4 + (l))    // ffn(l) published partials: +32/step
#define FL_FXF(j) (8 + (j))    // xfin published, replicated: +8/step per line
#define FL_FFC(j) (16 + (j))   // fc done, replicated by bid&7: +32/step per line
#define FL_MEM    24
#define FL_CA     25

// float offsets in d_ws (flow path); flags occupy words 0..2047
#define WS_MEMB 2048     // 2048
#define WS_CAB  4096     // 8192
#define WS_UB   12288    // 4*8*256 = 8192
#define WS_FFPB 20480    // 2*32*8*256 = 131072
#define WS_XF   151552   // 2048
#define WS_PVB  153600   // 2048
#define WS_PIB  155648   // 2048 ints

// fallback (round-1 proven) offsets
#define WS_MEM 0
#define WS_CA  2048
#define WS_X   10240
#define WS_Q   12288
#define WS_FFP 14336
#define WS_KC  79872
#define WS_VC  489472
#define WS_PV  899072
#define WS_PI  905472
#define WS_TOK 911872
#define FCT 786

// ---------- LLC-coherent helpers ----------
__device__ __forceinline__ float gld(const float* p) {
  return __hip_atomic_load(const_cast<float*>(p), __ATOMIC_RELAXED, __HIP_MEMORY_SCOPE_AGENT);
}
__device__ __forceinline__ void gst(float* p, float v) {
  __hip_atomic_store(p, v, __ATOMIC_RELAXED, __HIP_MEMORY_SCOPE_AGENT);
}
__device__ __forceinline__ int gldi(const int* p) {
  return __hip_atomic_load(const_cast<int*>(p), __ATOMIC_RELAXED, __HIP_MEMORY_SCOPE_AGENT);
}
__device__ __forceinline__ void gsti(int* p, int v) {
  __hip_atomic_store(p, v, __ATOMIC_RELAXED, __HIP_MEMORY_SCOPE_AGENT);
}
__device__ __forceinline__ unsigned fld(unsigned* p) {
  return __hip_atomic_load(p, __ATOMIC_RELAXED, __HIP_MEMORY_SCOPE_AGENT);
}
__device__ __forceinline__ void bump(unsigned* f) {
  asm volatile("s_waitcnt vmcnt(0)" ::: "memory");
  __syncthreads();
  if (threadIdx.x == 0)
    __hip_atomic_fetch_add(f, 1u, __ATOMIC_RELAXED, __HIP_MEMORY_SCOPE_AGENT);
}
__device__ __forceinline__ void waitf(unsigned* f, unsigned tgt) {
  if (threadIdx.x == 0) {
    while (fld(f) < tgt) __builtin_amdgcn_s_sleep(8);
  }
  __syncthreads();
}

__device__ __forceinline__ float block_ln256(float v, int tid, float* red8, float g, float bta) {
  float s = v, s2 = v * v;
#pragma unroll
  for (int m = 32; m >= 1; m >>= 1) { s += __shfl_xor(s, m); s2 += __shfl_xor(s2, m); }
  int w = tid >> 6;
  __syncthreads();
  if ((tid & 63) == 0) { red8[w] = s; red8[4 + w] = s2; }
  __syncthreads();
  s = red8[0] + red8[1] + red8[2] + red8[3];
  s2 = red8[4] + red8[5] + red8[6] + red8[7];
  float mn = s * (1.0f / 256.0f);
  float var = s2 * (1.0f / 256.0f) - mn * mn;
  float rs = rsqrtf(var + LNEPS);
  return (v - mn) * rs * g + bta;
}

// fc GEMV + per-block argmax partial (numerics identical to proven path)
__device__ __forceinline__ void fc_phase(int bid, int tid, int t,
                                         const float* xf, const float* fc_w,
                                         const float* fc_b, float* out,
                                         float* pv, int* pi,
                                         float* xl, float* rv, int* ri) {
  for (int b = 0; b < 8; ++b) xl[b * 260 + tid] = gld(xf + b * 256 + tid);
  __syncthreads();
  int r = tid >> 3, b = tid & 7;
  float bv = -3e38f; int bi = 2147483647;
  int base = bid * RPB;
  for (int i = 0; i < 7; ++i) {
    int rr = i * 32 + r, row = base + rr;
    if (rr < RPB && row < NV) {
      float acc = fc_b[row];
      const float4* w4 = reinterpret_cast<const float4*>(fc_w + (size_t)row * 256);
      const float4* xv = reinterpret_cast<const float4*>(xl + b * 260);
      for (int k = 0; k < 64; ++k) {
        float4 wv = w4[k]; float4 xq = xv[k];
        acc += wv.x * xq.x + wv.y * xq.y + wv.z * xq.z + wv.w * xq.w;
      }
      out[(size_t)(b * 49 + t) * NV + row] = acc;
      if (acc > bv || (acc == bv && row < bi)) { bv = acc; bi = row; }
    }
  }
  rv[tid] = bv; ri[tid] = bi;
  __syncthreads();
  for (int off = 128; off >= 8; off >>= 1) {
    if (tid < off) {
      float v = rv[tid + off]; int id = ri[tid + off];
      if (v > rv[tid] || (v == rv[tid] && id < ri[tid])) { rv[tid] = v; ri[tid] = id; }
    }
    __syncthreads();
  }
  if (tid < 8) { gst(pv + bid * 8 + tid, rv[tid]); gsti(pi + bid * 8 + tid, ri[tid]); }
}

// ================= single-dispatch dataflow kernel v2 =================
__global__ __launch_bounds__(256) void k_flow2(
    const float* __restrict__ emb, const float* __restrict__ w_proj, const float* __restrict__ b_proj,
    const float* __restrict__ tok_emb, const float* __restrict__ pos_enc,
    const float* __restrict__ sa_in_w, const float* __restrict__ sa_in_b,
    const float* __restrict__ sa_out_w, const float* __restrict__ sa_out_b,
    const float* __restrict__ ca_in_w, const float* __restrict__ ca_in_b,
    const float* __restrict__ ca_out_w, const float* __restrict__ ca_out_b,
    const float* __restrict__ ff1_w, const float* __restrict__ ff1_b,
    const float* __restrict__ ff2_w, const float* __restrict__ ff2_b,
    const float* __restrict__ ln_g, const float* __restrict__ ln_b,
    const float* __restrict__ fc_w, const float* __restrict__ fc_b,
    float* __restrict__ out, float* __restrict__ wsf, int* __restrict__ wsi) {
  extern __shared__ float dynlds[];   // owners: K [256][52] d-major + V [50][256]
  const int bid = blockIdx.x, tid = threadIdx.x;

  unsigned* FL = (unsigned*)wsf;
  float* mem = wsf + WS_MEMB;
  float* ca  = wsf + WS_CAB;
  float* u   = wsf + WS_UB;
  float* ffp = wsf + WS_FFPB;
  float* xf  = wsf + WS_XF;
  float* pv  = wsf + WS_PVB;
  int*   pi  = wsi + WS_PIB;

  __shared__ float xl[8 * 260];
  __shared__ float h1l[64 * 9];
  __shared__ float ql[256], ol[256], ph[8 * 64];
  __shared__ float xrow[256];
  __shared__ float red8[8];
  __shared__ float rv[256];
  __shared__ int   ri[256];
  __shared__ int   toks[8];
  __shared__ float el[1536];

  // ---- init 1: mem = embedding @ w_proj.T + b_proj (blocks 0..63)
  if (bid < 64) {
    int b = bid >> 3, tile = bid & 7;
    for (int k = tid; k < 1536; k += 256) el[k] = emb[b * 1536 + k];
    __syncthreads();
    int r = tid >> 3, g = tid & 7;
    int row = tile * 32 + r;
    float acc = 0.f;
    const float* wr = w_proj + (size_t)row * 1536;
    for (int c = g * 192; c < g * 192 + 192; ++c) acc += wr[c] * el[c];
    rv[tid] = acc;
    __syncthreads();
    for (int off = 4; off >= 1; off >>= 1) {
      if (g < off) rv[tid] += rv[tid + off];
      __syncthreads();
    }
    if (g == 0) gst(mem + b * 256 + row, rv[tid] + b_proj[row]);
    bump(FL + FL_MEM * FSTRIDE);
  }
  // ---- init 2: cross-attn constant (memory len 1 => attn == V_mem) (blocks 64..95)
  if (bid >= 64 && bid < 96) {
    waitf(FL + FL_MEM * FSTRIDE, 64u);
    int l = (bid - 64) >> 3, b = (bid - 64) & 7;
    ql[tid] = gld(mem + b * 256 + tid);
    __syncthreads();
    float acc = ca_in_b[l * 768 + 512 + tid];
    const float* wr = ca_in_w + (size_t)(l * 768 + 512 + tid) * 256;
    for (int c = 0; c < 256; ++c) acc += wr[c] * ql[c];
    ol[tid] = acc;
    __syncthreads();
    float acc2 = ca_out_b[l * 256 + tid];
    const float* wr2 = ca_out_w + (size_t)(l * 256 + tid) * 256;
    for (int c = 0; c < 256; ++c) acc2 += wr2[c] * ol[c];
    gst(ca + (l * 8 + b) * 256 + tid, acc2);
    bump(FL + FL_CA * FSTRIDE);
  }

  if (bid < 32) {
    // ======= OWNER role: block = (layer myl, batch myb). qkv+attn+proj+LN in one stage. =======
    int myl = bid >> 3, myb = bid & 7;
    float* Klds = dynlds;             // [256][52] d-major
    float* Vlds = dynlds + 256 * 52;  // [50][256]
    waitf(FL + FL_CA * FSTRIDE, 32u);
    for (int t = 0; t < NSTEP; ++t) {
      float xval;
      if (myl == 0) {
        if (t > 0) {
          if (tid == 0) {  // all fc of step t-1 done (sum of 8 monotone lines)
            for (;;) {
              unsigned s = 0;
              for (int j = 0; j < 8; ++j) s += fld(FL + FL_FFC(j) * FSTRIDE);
              if (s >= 256u * (unsigned)t) break;
              __builtin_amdgcn_s_sleep(8);
            }
          }
          __syncthreads();
          rv[tid] = gld(pv + tid * 8 + myb); ri[tid] = gldi(pi + tid * 8 + myb);
          __syncthreads();
          for (int off = 128; off >= 1; off >>= 1) {
            if (tid < off) {
              float v = rv[tid + off]; int id = ri[tid + off];
              if (v > rv[tid] || (v == rv[tid] && id < ri[tid])) { rv[tid] = v; ri[tid] = id; }
            }
            __syncthreads();
          }
          if (tid == 0) toks[0] = ri[0];
          __syncthreads();
        } else {
          if (tid == 0) toks[0] = BOSTOK;
          __syncthreads();
        }
        xval = tok_emb[(size_t)toks[0] * 256 + tid] + pos_enc[t * 256 + tid];
      } else {
        waitf(FL + FL_FP(myl - 1) * FSTRIDE, 32u * (unsigned)(t + 1));
        int par = (myl - 1) & 1;
        float a = gld(u + ((myl - 1) * 8 + myb) * 256 + tid) + ff2_b[(myl - 1) * 256 + tid];
        for (int s = 0; s < 32; ++s) a += gld(ffp + par * 65536 + (s * 8 + myb) * 256 + tid);
        xval = block_ln256(a, tid, red8, ln_g[((myl - 1) * 3 + 2) * 256 + tid],
                           ln_b[((myl - 1) * 3 + 2) * 256 + tid]);
      }
      xrow[tid] = xval;
      __syncthreads();
      // qkv: thread handles rows tid, tid+256, tid+512 -> LDS (no global staging)
#pragma unroll
      for (int rr = 0; rr < 3; ++rr) {
        int row = tid + rr * 256;
        float acc = sa_in_b[myl * 768 + row];
        const float4* w4 = reinterpret_cast<const float4*>(sa_in_w + (size_t)(myl * 768 + row) * 256);
        const float4* xv = reinterpret_cast<const float4*>(xrow);
#pragma unroll 8
        for (int k = 0; k < 64; ++k) {
          float4 wv = w4[k]; float4 xq = xv[k];
          acc += wv.x * xq.x + wv.y * xq.y + wv.z * xq.z + wv.w * xq.w;
        }
        if (rr == 0) ql[tid] = acc;
        else if (rr == 1) Klds[tid * 52 + t] = acc;
        else Vlds[t * 256 + tid] = acc;
      }
      __syncthreads();
      // attention for (myl, myb)
      int h = tid >> 5, j0 = tid & 31;
      const float* qh = ql + h * 32;
      float s0 = -3e38f, s1 = -3e38f;
      if (j0 <= t) {
        float d0 = 0.f;
#pragma unroll
        for (int d = 0; d < 32; ++d) d0 += qh[d] * Klds[(h * 32 + d) * 52 + j0];
        s0 = d0 * 0.17677669529663687f;
      }
      if (j0 + 32 <= t) {
        float d1 = 0.f;
#pragma unroll
        for (int d = 0; d < 32; ++d) d1 += qh[d] * Klds[(h * 32 + d) * 52 + j0 + 32];
        s1 = d1 * 0.17677669529663687f;
      }
      float mx = fmaxf(s0, s1);
      for (int m = 16; m >= 1; m >>= 1) mx = fmaxf(mx, __shfl_xor(mx, m, 32));
      float e0 = (j0 <= t) ? expf(s0 - mx) : 0.f;
      float e1 = (j0 + 32 <= t) ? expf(s1 - mx) : 0.f;
      float sm = e0 + e1;
      for (int m = 16; m >= 1; m >>= 1) sm += __shfl_xor(sm, m, 32);
      ph[h * 64 + j0] = e0;
      ph[h * 64 + j0 + 32] = e1;
      __syncthreads();
      float o = 0.f;
      for (int j = 0; j <= t; ++j) o += ph[h * 64 + j] * Vlds[j * 256 + tid];
      ol[tid] = o / sm;
      __syncthreads();
      // out-proj + residual + LN0 + ca + LN1 -> publish u
      float acc = sa_out_b[myl * 256 + tid];
      const float4* w4 = reinterpret_cast<const float4*>(sa_out_w + (size_t)(myl * 256 + tid) * 256);
#pragma unroll 4
      for (int k = 0; k < 64; ++k) {
        float4 wv = w4[k];
        acc += wv.x * ol[4 * k] + wv.y * ol[4 * k + 1] + wv.z * ol[4 * k + 2] + wv.w * ol[4 * k + 3];
      }
      acc += xval;
      float y = block_ln256(acc, tid, red8, ln_g[(myl * 3 + 0) * 256 + tid],
                            ln_b[(myl * 3 + 0) * 256 + tid]);
      float y2 = block_ln256(y + gld(ca + (myl * 8 + myb) * 256 + tid), tid, red8,
                             ln_g[(myl * 3 + 1) * 256 + tid], ln_b[(myl * 3 + 1) * 256 + tid]);
      gst(u + (myl * 8 + myb) * 256 + tid, y2);
      bump(FL + FL_FU(myl) * FSTRIDE);

      if (myl == 0) {
        // xfin: final LN after layer-3 FFN
        waitf(FL + FL_FP(3) * FSTRIDE, 32u * (unsigned)(t + 1));
        float a = gld(u + (3 * 8 + myb) * 256 + tid) + ff2_b[3 * 256 + tid];
        for (int s = 0; s < 32; ++s) a += gld(ffp + 65536 + (s * 8 + myb) * 256 + tid);  // par(l=3)=1
        float xfv = block_ln256(a, tid, red8, ln_g[(3 * 3 + 2) * 256 + tid],
                                ln_b[(3 * 3 + 2) * 256 + tid]);
        gst(xf + myb * 256 + tid, xfv);
        asm volatile("s_waitcnt vmcnt(0)" ::: "memory");
        __syncthreads();
        if (tid == 0)
          for (int j = 0; j < 8; ++j)
            __hip_atomic_fetch_add(FL + FL_FXF(j) * FSTRIDE, 1u, __ATOMIC_RELAXED,
                                   __HIP_MEMORY_SCOPE_AGENT);
      }
      // fc
      waitf(FL + FL_FXF(bid & 7) * FSTRIDE, 8u * (unsigned)(t + 1));
      fc_phase(bid, tid, t, xf, fc_w, fc_b, out, pv, pi, xl, rv, ri);
      bump(FL + FL_FFC(bid & 7) * FSTRIDE);
    }
  } else if (bid < 64) {
    // ======= FFN role: block owns 64 neurons (slice s), iterates layers =======
    int s = bid - 32;
    for (int t = 0; t < NSTEP; ++t) {
      for (int l = 0; l < 4; ++l) {
        waitf(FL + FL_FU(l) * FSTRIDE, 8u * (unsigned)(t + 1));
        for (int b = 0; b < 8; ++b) xl[b * 260 + tid] = gld(u + (l * 8 + b) * 256 + tid);
        __syncthreads();
        int n0 = tid >> 3, b = tid & 7;
#pragma unroll
        for (int i = 0; i < 2; ++i) {
          int nn = n0 + i * 32, row = s * 64 + nn;
          float acc = ff1_b[l * 2048 + row];
          const float4* w4 = reinterpret_cast<const float4*>(ff1_w + (size_t)(l * 2048 + row) * 256);
          const float4* xv = reinterpret_cast<const float4*>(xl + b * 260);
          for (int k = 0; k < 64; ++k) {
            float4 wv = w4[k]; float4 xq = xv[k];
            acc += wv.x * xq.x + wv.y * xq.y + wv.z * xq.z + wv.w * xq.w;
          }
          h1l[nn * 9 + b] = fmaxf(acc, 0.f);
        }
        __syncthreads();
        float facc[8] = {0, 0, 0, 0, 0, 0, 0, 0};
        const float* w2p = ff2_w + (size_t)(l * 256 + tid) * 2048 + s * 64;
        for (int n = 0; n < 64; ++n) {
          float wv = w2p[n];
#pragma unroll
          for (int b2 = 0; b2 < 8; ++b2) facc[b2] += wv * h1l[n * 9 + b2];
        }
        int par = l & 1;
        for (int b2 = 0; b2 < 8; ++b2)
          gst(ffp + par * 65536 + (s * 8 + b2) * 256 + tid, facc[b2]);
        bump(FL + FL_FP(l) * FSTRIDE);
      }
      waitf(FL + FL_FXF(bid & 7) * FSTRIDE, 8u * (unsigned)(t + 1));
      fc_phase(bid, tid, t, xf, fc_w, fc_b, out, pv, pi, xl, rv, ri);
      bump(FL + FL_FFC(bid & 7) * FSTRIDE);
    }
  } else {
    // ======= fc-only role =======
    for (int t = 0; t < NSTEP; ++t) {
      waitf(FL + FL_FXF(bid & 7) * FSTRIDE, 8u * (unsigned)(t + 1));
      fc_phase(bid, tid, t, xf, fc_w, fc_b, out, pv, pi, xl, rv, ri);
      bump(FL + FL_FFC(bid & 7) * FSTRIDE);
    }
  }
}

// ================= fallback path (round-1, proven at 13.7 ms) =================
__device__ __forceinline__ float block_ln(float v, int tid, float* red, float* red2,
                                          float g, float bta) {
  red[tid] = v; red2[tid] = v * v;
  __syncthreads();
  for (int off = 128; off > 0; off >>= 1) {
    if (tid < off) { red[tid] += red[tid + off]; red2[tid] += red2[tid + off]; }
    __syncthreads();
  }
  float m = red[0] * (1.0f / 256.0f);
  float var = red2[0] * (1.0f / 256.0f) - m * m;
  float rs = rsqrtf(var + LNEPS);
  float y = (v - m) * rs * g + bta;
  __syncthreads();
  return y;
}

__global__ __launch_bounds__(256) void k_mem(const float* __restrict__ emb,
                                             const float* __restrict__ w,
                                             const float* __restrict__ bias,
                                             float* __restrict__ mem) {
  __shared__ float el[1536];
  __shared__ float red[256];
  int b = blockIdx.x >> 3, tile = blockIdx.x & 7, tid = threadIdx.x;
  for (int k = tid; k < 1536; k += 256) el[k] = emb[b * 1536 + k];
  __syncthreads();
  int r = tid >> 3, g = tid & 7;
  int row = tile * 32 + r;
  float acc = 0.f;
  const float* wr = w + row * 1536;
  for (int c = g * 192; c < g * 192 + 192; ++c) acc += wr[c] * el[c];
  red[tid] = acc;
  __syncthreads();
  for (int off = 4; off >= 1; off >>= 1) {
    if (g < off) red[tid] += red[tid + off];
    __syncthreads();
  }
  if (g == 0) mem[b * 256 + row] = red[tid] + bias[row];
}

__global__ __launch_bounds__(256) void k_ca(const float* __restrict__ mem,
                                            const float* __restrict__ iw,
                                            const float* __restrict__ ib,
                                            const float* __restrict__ ow,
                                            const float* __restrict__ ob,
                                            float* __restrict__ ca) {
  __shared__ float ml[256], vl[256];
  int l = blockIdx.x >> 3, b = blockIdx.x & 7, tid = threadIdx.x;
  ml[tid] = mem[b * 256 + tid];
  __syncthreads();
  float acc = ib[l * 768 + 512 + tid];
  const float* wr = iw + (size_t)(l * 768 + 512 + tid) * 256;
  for (int c = 0; c < 256; ++c) acc += wr[c] * ml[c];
  vl[tid] = acc;
  __syncthreads();
  float acc2 = ob[l * 256 + tid];
  const float* wr2 = ow + (size_t)(l * 256 + tid) * 256;
  for (int c = 0; c < 256; ++c) acc2 += wr2[c] * vl[c];
  ca[(l * 8 + b) * 256 + tid] = acc2;
}

__global__ void k_tok_init(int* __restrict__ tok) {
  if (threadIdx.x < 8) tok[threadIdx.x * 64] = BOSTOK;
}

__global__ __launch_bounds__(256) void k_embed(const int* __restrict__ tok,
                                               const float* __restrict__ te,
                                               const float* __restrict__ pe,
                                               float* __restrict__ x, int t) {
  int tid = threadIdx.x;
  for (int b = 0; b < 8; ++b) {
    int tk = tok[b * 64 + t];
    x[b * 256 + tid] = te[(size_t)tk * 256 + tid] + pe[t * 256 + tid];
  }
}

__global__ __launch_bounds__(256) void k_qkv(const float* __restrict__ x,
                                             const float* __restrict__ w,
                                             const float* __restrict__ bias,
                                             float* __restrict__ q,
                                             float* __restrict__ kc,
                                             float* __restrict__ vc, int l, int t) {
  __shared__ float xl[8 * 260];
  int tid = threadIdx.x;
  for (int k = 0; k < 8; ++k) {
    int idx = tid + k * 256;
    xl[(idx >> 8) * 260 + (idx & 255)] = x[idx];
  }
  __syncthreads();
  int r = tid >> 3, b = tid & 7;
  int row = blockIdx.x * 32 + r;
  float acc = bias[l * 768 + row];
  const float4* w4 = reinterpret_cast<const float4*>(w + (size_t)(l * 768 + row) * 256);
  const float4* xv = reinterpret_cast<const float4*>(xl + b * 260);
#pragma unroll 8
  for (int k = 0; k < 64; ++k) {
    float4 wv = w4[k]; float4 xq = xv[k];
    acc += wv.x * xq.x + wv.y * xq.y + wv.z * xq.z + wv.w * xq.w;
  }
  if (row < 256) {
    q[b * 256 + row] = acc;
  } else if (row < 512) {
    int h = (row - 256) >> 5, d = (row - 256) & 31;
    kc[(((l * 8 + b) * 8 + h) * 50 + t) * 32 + d] = acc;
  } else {
    int h = (row - 512) >> 5, d = (row - 512) & 31;
    vc[(((l * 8 + b) * 8 + h) * 50 + t) * 32 + d] = acc;
  }
}

__global__ __launch_bounds__(256) void k_attn(const float* __restrict__ q,
                                              float* __restrict__ x,
                                              const float* __restrict__ kc,
                                              const float* __restrict__ vc,
                                              const float* __restrict__ ow,
                                              const float* __restrict__ ob,
                                              const float* __restrict__ lg,
                                              const float* __restrict__ lb,
                                              const float* __restrict__ ca, int l, int t) {
  __shared__ float ql[256], ol[256], sc[64], red[256], red2[256];
  __shared__ float ssum;
  int b = blockIdx.x, tid = threadIdx.x;
  float xres = x[b * 256 + tid];
  ql[tid] = q[b * 256 + tid];
  __syncthreads();
  for (int h = 0; h < 8; ++h) {
    const float* kb = kc + (size_t)(((l * 8 + b) * 8 + h) * 50) * 32;
    if (tid <= t) {
      float s = 0.f;
      const float* kr = kb + tid * 32;
#pragma unroll
      for (int d = 0; d < 32; ++d) s += ql[h * 32 + d] * kr[d];
      sc[tid] = s * 0.17677669529663687f;
    }
    __syncthreads();
    if (tid < 64) {
      float v = (tid <= t) ? sc[tid] : -1e30f;
      float mx = v;
      for (int m = 32; m >= 1; m >>= 1) mx = fmaxf(mx, __shfl_xor(mx, m));
      float e = (tid <= t) ? expf(sc[tid] - mx) : 0.f;
      sc[tid] = e;
      float sm = e;
      for (int m = 32; m >= 1; m >>= 1) sm += __shfl_xor(sm, m);
      if (tid == 0) ssum = sm;
    }
    __syncthreads();
    if (tid < 32) {
      const float* vb = vc + (size_t)(((l * 8 + b) * 8 + h) * 50) * 32 + tid;
      float acc = 0.f;
      for (int j = 0; j <= t; ++j) acc += sc[j] * vb[j * 32];
      ol[h * 32 + tid] = acc / ssum;
    }
    __syncthreads();
  }
  float acc = ob[l * 256 + tid];
  const float4* w4 = reinterpret_cast<const float4*>(ow + (size_t)(l * 256 + tid) * 256);
#pragma unroll 4
  for (int k = 0; k < 64; ++k) {
    float4 wv = w4[k];
    acc += wv.x * ol[4 * k] + wv.y * ol[4 * k + 1] + wv.z * ol[4 * k + 2] + wv.w * ol[4 * k + 3];
  }
  acc += xres;
  float y = block_ln(acc, tid, red, red2, lg[(l * 3 + 0) * 256 + tid], lb[(l * 3 + 0) * 256 + tid]);
  float acc2 = y + ca[(l * 8 + b) * 256 + tid];
  float y2 = block_ln(acc2, tid, red, red2, lg[(l * 3 + 1) * 256 + tid], lb[(l * 3 + 1) * 256 + tid]);
  x[b * 256 + tid] = y2;
}

__global__ __launch_bounds__(256) void k_ffn(const float* __restrict__ x,
                                             const float* __restrict__ w1,
                                             const float* __restrict__ b1,
                                             const float* __restrict__ w2,
                                             float* __restrict__ ffp, int l) {
  __shared__ float xl[8 * 260];
  __shared__ float h1l[64 * 9];
  int tid = threadIdx.x, s = blockIdx.x;
  for (int k = 0; k < 8; ++k) {
    int idx = tid + k * 256;
    xl[(idx >> 8) * 260 + (idx & 255)] = x[idx];
  }
  __syncthreads();
  int n0 = tid >> 3, b = tid & 7;
#pragma unroll
  for (int i = 0; i < 2; ++i) {
    int nn = n0 + i * 32, row = s * 64 + nn;
    float acc = b1[l * 2048 + row];
    const float4* w4 = reinterpret_cast<const float4*>(w1 + (size_t)(l * 2048 + row) * 256);
    const float4* xv = reinterpret_cast<const float4*>(xl + b * 260);
    for (int k = 0; k < 64; ++k) {
      float4 wv = w4[k]; float4 xq = xv[k];
      acc += wv.x * xq.x + wv.y * xq.y + wv.z * xq.z + wv.w * xq.w;
    }
    h1l[nn * 9 + b] = fmaxf(acc, 0.f);
  }
  __syncthreads();
  int row = tid;
  float acc[8] = {0, 0, 0, 0, 0, 0, 0, 0};
  const float* w2p = w2 + (size_t)(l * 256 + row) * 2048 + s * 64;
  for (int n = 0; n < 64; ++n) {
    float wv = w2p[n];
#pragma unroll
    for (int b2 = 0; b2 < 8; ++b2) acc[b2] += wv * h1l[n * 9 + b2];
  }
  for (int b2 = 0; b2 < 8; ++b2) ffp[(s * 8 + b2) * 256 + row] = acc[b2];
}

__global__ __launch_bounds__(256) void k_ffred(float* __restrict__ x,
                                               const float* __restrict__ ffp,
                                               const float* __restrict__ b2,
                                               const float* __restrict__ lg,
                                               const float* __restrict__ lb, int l) {
  __shared__ float red[256], red2[256];
  int b = blockIdx.x, tid = threadIdx.x;
  float acc = b2[l * 256 + tid] + x[b * 256 + tid];
  for (int s = 0; s < 32; ++s) acc += ffp[(s * 8 + b) * 256 + tid];
  float y = block_ln(acc, tid, red, red2, lg[(l * 3 + 2) * 256 + tid], lb[(l * 3 + 2) * 256 + tid]);
  x[b * 256 + tid] = y;
}

__global__ __launch_bounds__(256) void k_fc(const float* __restrict__ h,
                                            const float* __restrict__ w,
                                            const float* __restrict__ bias,
                                            float* __restrict__ out,
                                            float* __restrict__ pv,
                                            int* __restrict__ pi, int t) {
  __shared__ float hl[8 * 260];
  __shared__ float rv[256];
  __shared__ int ri[256];
  int tid = threadIdx.x, wg = blockIdx.x;
  for (int k = 0; k < 8; ++k) {
    int idx = tid + k * 256;
    hl[(idx >> 8) * 260 + (idx & 255)] = h[idx];
  }
  __syncthreads();
  int r = tid >> 3, b = tid & 7;
  float bv = -3e38f;
  int bi = 2147483647;
  for (int i = 0; i < 2; ++i) {
    int row = wg * 64 + i * 32 + r;
    if (row < NV) {
      float acc = bias[row];
      const float4* w4 = reinterpret_cast<const float4*>(w + (size_t)row * 256);
      const float4* xv = reinterpret_cast<const float4*>(hl + b * 260);
      for (int k = 0; k < 64; ++k) {
        float4 wv = w4[k]; float4 xq = xv[k];
        acc += wv.x * xq.x + wv.y * xq.y + wv.z * xq.z + wv.w * xq.w;
      }
      out[(size_t)(b * 49 + t) * NV + row] = acc;
      if (acc > bv || (acc == bv && row < bi)) { bv = acc; bi = row; }
    }
  }
  rv[tid] = bv; ri[tid] = bi;
  __syncthreads();
  for (int off = 128; off >= 8; off >>= 1) {
    if (tid < off) {
      float v = rv[tid + off]; int id = ri[tid + off];
      if (v > rv[tid] || (v == rv[tid] && id < ri[tid])) { rv[tid] = v; ri[tid] = id; }
    }
    __syncthreads();
  }
  if (tid < 8) { pv[wg * 8 + tid] = rv[tid]; pi[wg * 8 + tid] = ri[tid]; }
}

__global__ __launch_bounds__(256) void k_amax(const float* __restrict__ pv,
                                              const int* __restrict__ pi,
                                              int* __restrict__ tok, int t) {
  __shared__ float rv[256];
  __shared__ int ri[256];
  int tid = threadIdx.x, b = tid & 7, i0 = tid >> 3;
  float bv = -3e38f;
  int bi = 2147483647;
  for (int p = i0; p < FCT; p += 32) {
    float v = pv[p * 8 + b]; int id = pi[p * 8 + b];
    if (v > bv || (v == bv && id < bi)) { bv = v; bi = id; }
  }
  rv[tid] = bv; ri[tid] = bi;
  __syncthreads();
  for (int off = 128; off >= 8; off >>= 1) {
    if (tid < off) {
      float v = rv[tid + off]; int id = ri[tid + off];
      if (v > rv[tid] || (v == rv[tid] && id < ri[tid])) { rv[tid] = v; ri[tid] = id; }
    }
    __syncthreads();
  }
  if (tid < 8) tok[tid * 64 + t + 1] = ri[tid];
}

extern "C" void kernel_launch(void* const* d_in, const int* in_sizes, int n_in,
                              void* d_out, int out_size, void* d_ws, size_t ws_size,
                              hipStream_t stream) {
  (void)in_sizes; (void)n_in; (void)out_size; (void)ws_size;
  const float* embedding = (const float*)d_in[0];
  const float* w_proj   = (const float*)d_in[1];
  const float* b_proj   = (const float*)d_in[2];
  const float* tok_emb  = (const float*)d_in[3];
  const float* pos_enc  = (const float*)d_in[4];
  const float* sa_in_w  = (const float*)d_in[5];
  const float* sa_in_b  = (const float*)d_in[6];
  const float* sa_out_w = (const float*)d_in[7];
  const float* sa_out_b = (const float*)d_in[8];
  const float* ca_in_w  = (const float*)d_in[9];
  const float* ca_in_b  = (const float*)d_in[10];
  const float* ca_out_w = (const float*)d_in[11];
  const float* ca_out_b = (const float*)d_in[12];
  const float* ff1_w    = (const float*)d_in[13];
  const float* ff1_b    = (const float*)d_in[14];
  const float* ff2_w    = (const float*)d_in[15];
  const float* ff2_b    = (const float*)d_in[16];
  const float* ln_g     = (const float*)d_in[17];
  const float* ln_b     = (const float*)d_in[18];
  const float* fc_w     = (const float*)d_in[19];
  const float* fc_b     = (const float*)d_in[20];
  float* out = (float*)d_out;
  float* wsf = (float*)d_ws;
  int*   wsi = (int*)d_ws;

  int dev = 0;
  (void)hipGetDevice(&dev);
  int coopAttr = 0;
  (void)hipDeviceGetAttribute(&coopAttr, hipDeviceAttributeCooperativeLaunch, dev);
  int ncu = 0;
  (void)hipDeviceGetAttribute(&ncu, hipDeviceAttributeMultiprocessorCount, dev);
  (void)hipFuncSetAttribute(reinterpret_cast<const void*>(k_flow2),
                            hipFuncAttributeMaxDynamicSharedMemorySize, DYN_LDS_BYTES);
  int maxb = 0;
  hipError_t oe = hipOccupancyMaxActiveBlocksPerMultiprocessor(&maxb, k_flow2, 256, DYN_LDS_BYTES);

  bool coop_ok = (coopAttr != 0) && (oe == hipSuccess) && ((long)maxb * (long)ncu >= NBLK);

  if (coop_ok) {
    (void)hipMemsetAsync(d_ws, 0, 8192, stream);  // zero flag lines
    void* args[] = {
        (void*)&embedding, (void*)&w_proj, (void*)&b_proj, (void*)&tok_emb, (void*)&pos_enc,
        (void*)&sa_in_w, (void*)&sa_in_b, (void*)&sa_out_w, (void*)&sa_out_b,
        (void*)&ca_in_w, (void*)&ca_in_b, (void*)&ca_out_w, (void*)&ca_out_b,
        (void*)&ff1_w, (void*)&ff1_b, (void*)&ff2_w, (void*)&ff2_b,
        (void*)&ln_g, (void*)&ln_b, (void*)&fc_w, (void*)&fc_b,
        (void*)&out, (void*)&wsf, (void*)&wsi};
    hipError_t le = hipLaunchCooperativeKernel((void*)k_flow2, dim3(NBLK), dim3(256),
                                               args, DYN_LDS_BYTES, stream);
    if (le != hipSuccess) coop_ok = false;
  }

  if (!coop_ok) {
    float* mem = wsf + WS_MEM;
    float* ca  = wsf + WS_CA;
    float* x   = wsf + WS_X;
    float* q   = wsf + WS_Q;
    float* ffp = wsf + WS_FFP;
    float* kc  = wsf + WS_KC;
    float* vc  = wsf + WS_VC;
    float* pv  = wsf + WS_PV;
    int*   pi  = wsi + WS_PI;
    int*   tok = wsi + WS_TOK;

    k_mem<<<64, 256, 0, stream>>>(embedding, w_proj, b_proj, mem);
    k_ca<<<32, 256, 0, stream>>>(mem, ca_in_w, ca_in_b, ca_out_w, ca_out_b, ca);
    k_tok_init<<<1, 64, 0, stream>>>(tok);

    for (int t = 0; t < NSTEP; ++t) {
      k_embed<<<1, 256, 0, stream>>>(tok, tok_emb, pos_enc, x, t);
      for (int l = 0; l < 4; ++l) {
        k_qkv<<<24, 256, 0, stream>>>(x, sa_in_w, sa_in_b, q, kc, vc, l, t);
        k_attn<<<8, 256, 0, stream>>>(q, x, kc, vc, sa_out_w, sa_out_b, ln_g, ln_b, ca, l, t);
        k_ffn<<<32, 256, 0, stream>>>(x, ff1_w, ff1_b, ff2_w, ffp, l);
        k_ffred<<<8, 256, 0, stream>>>(x, ffp, ff2_b, ln_g, ln_b, l);
      }
      k_fc<<<FCT, 256, 0, stream>>>(x, fc_w, fc_b, out, pv, pi, t);
      k_amax<<<1, 256, 0, stream>>>(pv, pi, tok, t);
    }
  }
}